// Round 4
// baseline (73341.888 us; speedup 1.0000x reference)
//
#include <hip/hip_runtime.h>
#include <hip/hip_fp16.h>

#define HDIM 256
#define LSEQ 512
#define PRED 96
#define NTHR 512

__device__ __forceinline__ float sigm(float x) { return 1.f / (1.f + __expf(-x)); }
// tanh(x) = 1 - 2/(e^{2x}+1); NaN-free at +/-inf
__device__ __forceinline__ float tanh_(float x) { float t = __expf(2.f * x); return 1.f - 2.f / (t + 1.f); }

struct SmemT {
  float h[2][2][132];    // [buf][k-half][128 + pad4] fp32 hidden state
  float stg[2][2][132];  // P2 input staging (same layout)
  float xv[LSEQ];
  float wih[768];        // rank-1 input weights for scalar-input phases
  float bih[768];
  float bhh[768];
  float wo[HDIM];
  float red[8];
  float inp;
};

// Load this thread's 3 gate rows (128-wide k-slice) of a [768][256] fp32 matrix into
// packed f16 registers. Fully unrolled -> compile-time indices -> stays in VGPRs.
// 192 half2 VGPRs/thread x 512 thr = 384 KB/CU (fits the 512 KB RF; fp32 would not).
#define LOADW(PTR)                                                                 \
  {                                                                                \
    _Pragma("unroll") for (int g = 0; g < 3; ++g) {                                \
      const float2* rp = (const float2*)((PTR) + (j + (g << 8)) * HDIM + k0);      \
      _Pragma("unroll") for (int p = 0; p < 64; ++p) {                             \
        float2 f = rp[p];                                                          \
        w[g * 64 + p] = __floats2half2_rn(f.x, f.y);                               \
      }                                                                            \
    }                                                                              \
  }

// 3-gate partial dot over this thread's 128-wide k-slice, then pair-combine with the
// other k-half (lane^1, same wave). fmaf((float)h16, f32, f32) -> v_fma_mix_f32.
#define MATVEC(HP)                                                                 \
  {                                                                                \
    ar = 0.f; az = 0.f; an = 0.f;                                                  \
    const float2* hp2 = (const float2*)(HP);                                       \
    _Pragma("unroll") for (int p = 0; p < 64; ++p) {                               \
      float2 hv = hp2[p];                                                          \
      ar = fmaf(__low2float(w[p]), hv.x, ar);                                      \
      ar = fmaf(__high2float(w[p]), hv.y, ar);                                     \
      az = fmaf(__low2float(w[64 + p]), hv.x, az);                                 \
      az = fmaf(__high2float(w[64 + p]), hv.y, az);                                \
      an = fmaf(__low2float(w[128 + p]), hv.x, an);                                \
      an = fmaf(__high2float(w[128 + p]), hv.y, an);                               \
    }                                                                              \
    ar += __shfl_xor(ar, 1); az += __shfl_xor(az, 1); an += __shfl_xor(an, 1);     \
  }

// NOTE: 2nd launch_bounds arg behaves as CUDA minBlocksPerMultiprocessor on this
// toolchain (R2: (1024,4)->64 VGPR cap; R3: (512,2)->128 VGPR cap; both = 2048/waves).
// (512,1) -> 8 waves/CU -> 256-VGPR cap; w[192]+temps ~230 fits -> no scratch spill.
__global__ __launch_bounds__(NTHR, 1) void gru_forecast(
    const float* __restrict__ x,
    const float* __restrict__ Wih0, const float* __restrict__ Whh0,
    const float* __restrict__ bih0, const float* __restrict__ bhh0,
    const float* __restrict__ Wih1, const float* __restrict__ Whh1,
    const float* __restrict__ bih1, const float* __restrict__ bhh1,
    const float* __restrict__ Wdih, const float* __restrict__ Wdhh,
    const float* __restrict__ bdih, const float* __restrict__ bdhh,
    const float* __restrict__ Wo, const float* __restrict__ bo,
    float* __restrict__ out, __half* __restrict__ ys, __half* __restrict__ gi) {
  __shared__ SmemT s;
  const int tid = threadIdx.x;
  const int b = blockIdx.x;
  const int j = tid >> 1;      // output/gate row within H
  const int half = tid & 1;    // k-slice half
  const int k0 = half << 7;
  __half2 w[192];              // 3 gates x 64 half2 = this thread's weight slice
  float ar, az, an;

  // ---------------- Phase 1: encoder GRU layer 0 (input_size=1) ----------------
  s.xv[tid] = x[(size_t)b * LSEQ + tid];
  // NTHR=512 < 768 -> strided loop, NOT `if (tid<768)` (Round-0/1 NaN bug)
  for (int i = tid; i < 768; i += NTHR) {
    s.wih[i] = Wih0[i]; s.bih[i] = bih0[i]; s.bhh[i] = bhh0[i];
  }
  if (tid < 264) ((float*)s.h[0])[tid] = 0.f;
  LOADW(Whh0);
  __syncthreads();

  int pb = 0;
  for (int t = 0; t < LSEQ; ++t) {
    MATVEC(s.h[pb][half]);
    const float xt = s.xv[t];
    const float ghr = ar + s.bhh[j], ghz = az + s.bhh[j + 256], ghn = an + s.bhh[j + 512];
    const float r = sigm(fmaf(xt, s.wih[j], s.bih[j]) + ghr);
    const float z = sigm(fmaf(xt, s.wih[j + 256], s.bih[j + 256]) + ghz);
    const float n = tanh_(fmaf(r, ghn, fmaf(xt, s.wih[j + 512], s.bih[j + 512])));
    const float hold = s.h[pb][j >> 7][j & 127];
    const float hn = fmaf(z, hold - n, n);
    if (!half) {
      s.h[pb ^ 1][j >> 7][j & 127] = hn;
      ys[((size_t)b * LSEQ + t) * HDIM + j] = __float2half(hn);  // |h| < 1: f16-safe
    }
    pb ^= 1;
    __syncthreads();
  }

  // -------- Phase 2: GI1[t] = ys0[t] @ W_ih1.T + b_ih1 (no recurrence) --------
  LOADW(Wih1);
  for (int i = tid; i < 768; i += NTHR) s.bih[i] = bih1[i];
  if (tid < 128) {
    __half2 v = ((const __half2*)(ys + (size_t)b * LSEQ * HDIM))[tid];
    float2 f = __half22float2(v);
    s.stg[0][tid >> 6][(tid & 63) << 1] = f.x;
    s.stg[0][tid >> 6][((tid & 63) << 1) + 1] = f.y;
  }
  __syncthreads();
  for (int t = 0; t < LSEQ; ++t) {
    float2 nf;
    const bool ld = (t + 1 < LSEQ) && (tid < 128);
    if (ld) {
      __half2 v = ((const __half2*)(ys + ((size_t)b * LSEQ + t + 1) * HDIM))[tid];
      nf = __half22float2(v);
    }
    MATVEC(s.stg[t & 1][half]);
    if (!half) {
      const size_t o = ((size_t)b * LSEQ + t) * 768;
      gi[o + j] = __float2half(ar + s.bih[j]);
      gi[o + j + 256] = __float2half(az + s.bih[j + 256]);
      gi[o + j + 512] = __float2half(an + s.bih[j + 512]);
    }
    if (ld) {
      s.stg[(t + 1) & 1][tid >> 6][(tid & 63) << 1] = nf.x;
      s.stg[(t + 1) & 1][tid >> 6][((tid & 63) << 1) + 1] = nf.y;
    }
    __syncthreads();
  }

  // ---------------- Phase 3: encoder GRU layer 1 (uses precomputed GI) --------
  LOADW(Whh1);
  for (int i = tid; i < 768; i += NTHR) s.bhh[i] = bhh1[i];
  if (tid < 264) ((float*)s.h[0])[tid] = 0.f;
  __syncthreads();
  pb = 0;
  for (int t = 0; t < LSEQ; ++t) {
    const size_t o = ((size_t)b * LSEQ + t) * 768;
    const float gr = __half2float(gi[o + j]);           // prefetch before matvec;
    const float gz = __half2float(gi[o + j + 256]);     // latency hidden under fma_mix
    const float gn = __half2float(gi[o + j + 512]);
    MATVEC(s.h[pb][half]);
    const float ghr = ar + s.bhh[j], ghz = az + s.bhh[j + 256], ghn = an + s.bhh[j + 512];
    const float r = sigm(gr + ghr);
    const float z = sigm(gz + ghz);
    const float n = tanh_(fmaf(r, ghn, gn));
    const float hold = s.h[pb][j >> 7][j & 127];
    const float hn = fmaf(z, hold - n, n);
    if (!half) s.h[pb ^ 1][j >> 7][j & 127] = hn;
    pb ^= 1;
    __syncthreads();
  }

  // ---------------- Phase 4: autoregressive decoder (96 steps) ----------------
  LOADW(Wdhh);
  for (int i = tid; i < 768; i += NTHR) {
    s.wih[i] = Wdih[i]; s.bih[i] = bdih[i]; s.bhh[i] = bdhh[i];
  }
  if (tid < HDIM) s.wo[tid] = Wo[tid];
  if (tid == 0) s.inp = 0.f;
  const float bov = bo[0];
  __syncthreads();
  for (int t = 0; t < PRED; ++t) {
    const float it = s.inp;
    MATVEC(s.h[pb][half]);
    const float ghr = ar + s.bhh[j], ghz = az + s.bhh[j + 256], ghn = an + s.bhh[j + 512];
    const float r = sigm(fmaf(it, s.wih[j], s.bih[j]) + ghr);
    const float z = sigm(fmaf(it, s.wih[j + 256], s.bih[j + 256]) + ghz);
    const float n = tanh_(fmaf(r, ghn, fmaf(it, s.wih[j + 512], s.bih[j + 512])));
    const float hold = s.h[pb][j >> 7][j & 127];
    const float hn = fmaf(z, hold - n, n);
    float c = half ? 0.f : s.wo[j] * hn;
#pragma unroll
    for (int off = 1; off < 64; off <<= 1) c += __shfl_xor(c, off);
    if (!half) s.h[pb ^ 1][j >> 7][j & 127] = hn;
    if ((tid & 63) == 0) s.red[tid >> 6] = c;
    pb ^= 1;
    __syncthreads();
    if (tid == 0) {
      float ov = s.red[0] + s.red[1] + s.red[2] + s.red[3] +
                 s.red[4] + s.red[5] + s.red[6] + s.red[7] + bov;
      out[(size_t)b * PRED + t] = ov;
      s.inp = ov;
    }
    __syncthreads();
  }
}

extern "C" void kernel_launch(void* const* d_in, const int* in_sizes, int n_in,
                              void* d_out, int out_size, void* d_ws, size_t ws_size,
                              hipStream_t stream) {
  const float* x    = (const float*)d_in[0];
  const float* Wih0 = (const float*)d_in[1];
  const float* Whh0 = (const float*)d_in[2];
  const float* bih0 = (const float*)d_in[3];
  const float* bhh0 = (const float*)d_in[4];
  const float* Wih1 = (const float*)d_in[5];
  const float* Whh1 = (const float*)d_in[6];
  const float* bih1 = (const float*)d_in[7];
  const float* bhh1 = (const float*)d_in[8];
  const float* Wdih = (const float*)d_in[9];
  const float* Wdhh = (const float*)d_in[10];
  const float* bdih = (const float*)d_in[11];
  const float* bdhh = (const float*)d_in[12];
  const float* Wo   = (const float*)d_in[13];
  const float* bo   = (const float*)d_in[14];

  // ws layout: ys0 (f16, 256*512*256 = 64 MiB) | GI1 (f16, 256*512*768 = 192 MiB)
  __half* ys = (__half*)d_ws;
  __half* gi = ys + (size_t)256 * 512 * 256;

  gru_forecast<<<256, NTHR, 0, stream>>>(x, Wih0, Whh0, bih0, bhh0,
                                         Wih1, Whh1, bih1, bhh1,
                                         Wdih, Wdhh, bdih, bdhh, Wo, bo,
                                         (float*)d_out, ys, gi);
}

// Round 5
// 71241.675 us; speedup vs baseline: 1.0295x; 1.0295x over previous
//
#include <hip/hip_runtime.h>
#include <hip/hip_fp16.h>

#define HDIM 256
#define LSEQ 512
#define PRED 96
#define NTHR 512

typedef _Float16 h32 __attribute__((ext_vector_type(32)));  // 32 f16 = 16 VGPRs, pure SSA

__device__ __forceinline__ float sigm(float x) { return 1.f / (1.f + __expf(-x)); }
// tanh(x) = 1 - 2/(e^{2x}+1); NaN-free at +/-inf
__device__ __forceinline__ float tanh_(float x) { float t = __expf(2.f * x); return 1.f - 2.f / (t + 1.f); }

struct SmemT {
  float h[2][2][132];    // [buf][k-half][128 + pad4] fp32 hidden state (132*4B = 33*16B:
                         // float4-aligned; +4 dword skew keeps the 2 broadcast groups
                         // on disjoint banks)
  float stg[2][2][132];  // P2 input staging (same layout)
  float xv[LSEQ];
  float wih[768];        // rank-1 input weights for scalar-input phases
  float bih[768];
  float bhh[768];
  float wo[HDIM];
  float red[8];
  float inp;
};

// Fill one 32-wide f16 vector from 32 consecutive fp32 (RN truncation, same numerics
// as __floats2half_rn). Constant lane indices -> insertelement, no alloca.
#define LOAD32(V, SRC)                                                             \
  {                                                                                \
    const float4* q4 = (const float4*)(SRC);                                       \
    _Pragma("unroll") for (int p = 0; p < 8; ++p) {                                \
      float4 f = q4[p];                                                            \
      (V)[4 * p + 0] = (_Float16)f.x; (V)[4 * p + 1] = (_Float16)f.y;              \
      (V)[4 * p + 2] = (_Float16)f.z; (V)[4 * p + 3] = (_Float16)f.w;              \
    }                                                                              \
  }

// Load this thread's 3 gate rows (128-wide k-slice) of a [768][256] fp32 matrix into
// 12 named SSA f16 vectors (192 VGPRs total; 384 KB/CU <= 512 KB RF).
#define LOADW(PTR)                                                                 \
  {                                                                                \
    const float* r0 = (PTR) + (size_t)j * HDIM + k0;                               \
    const float* r1 = (PTR) + (size_t)(j + 256) * HDIM + k0;                       \
    const float* r2 = (PTR) + (size_t)(j + 512) * HDIM + k0;                       \
    LOAD32(wr0, r0); LOAD32(wr1, r0 + 32); LOAD32(wr2, r0 + 64); LOAD32(wr3, r0 + 96); \
    LOAD32(wz0, r1); LOAD32(wz1, r1 + 32); LOAD32(wz2, r1 + 64); LOAD32(wz3, r1 + 96); \
    LOAD32(wn0, r2); LOAD32(wn1, r2 + 32); LOAD32(wn2, r2 + 64); LOAD32(wn3, r2 + 96); \
  }

// One 32-wide segment of the 3-gate dot. One LDS float4 read feeds all 3 gates.
// fmaf((float)f16, f32, f32) -> v_fma_mix_f32.
#define DOT3SEG(Wr, Wz, Wn, H4)                                                    \
  {                                                                                \
    _Pragma("unroll") for (int p = 0; p < 8; ++p) {                                \
      float4 hv = (H4)[p];                                                         \
      ar = fmaf((float)(Wr)[4 * p + 0], hv.x, ar); ar = fmaf((float)(Wr)[4 * p + 1], hv.y, ar); \
      ar = fmaf((float)(Wr)[4 * p + 2], hv.z, ar); ar = fmaf((float)(Wr)[4 * p + 3], hv.w, ar); \
      az = fmaf((float)(Wz)[4 * p + 0], hv.x, az); az = fmaf((float)(Wz)[4 * p + 1], hv.y, az); \
      az = fmaf((float)(Wz)[4 * p + 2], hv.z, az); az = fmaf((float)(Wz)[4 * p + 3], hv.w, az); \
      an = fmaf((float)(Wn)[4 * p + 0], hv.x, an); an = fmaf((float)(Wn)[4 * p + 1], hv.y, an); \
      an = fmaf((float)(Wn)[4 * p + 2], hv.z, an); an = fmaf((float)(Wn)[4 * p + 3], hv.w, an); \
    }                                                                              \
  }

// 3-gate partial dot over this thread's 128-wide k-slice, then pair-combine with the
// other k-half (lane^1, same wave).
#define MATVEC(HP)                                                                 \
  {                                                                                \
    ar = 0.f; az = 0.f; an = 0.f;                                                  \
    const float4* h4 = (const float4*)(HP);                                        \
    DOT3SEG(wr0, wz0, wn0, h4);                                                    \
    DOT3SEG(wr1, wz1, wn1, h4 + 8);                                                \
    DOT3SEG(wr2, wz2, wn2, h4 + 16);                                               \
    DOT3SEG(wr3, wz3, wn3, h4 + 24);                                               \
    ar += __shfl_xor(ar, 1); az += __shfl_xor(az, 1); an += __shfl_xor(an, 1);     \
  }

// Evidence trail: __launch_bounds__ 2nd arg could not raise the VGPR cap past the
// backend's default occupancy target (R2: 64, R3/R4: 128 VGPRs -> 192-reg weight
// slice spilled to scratch, FETCH 64-117 GB, VALUBusy ~5%). amdgpu_waves_per_eu(2,2)
// is the native knob: max 2 waves/EU = 8 waves/CU -> 2048/8 = 256-VGPR budget.
__global__ __attribute__((amdgpu_flat_work_group_size(NTHR, NTHR), amdgpu_waves_per_eu(2, 2)))
void gru_forecast(
    const float* __restrict__ x,
    const float* __restrict__ Wih0, const float* __restrict__ Whh0,
    const float* __restrict__ bih0, const float* __restrict__ bhh0,
    const float* __restrict__ Wih1, const float* __restrict__ Whh1,
    const float* __restrict__ bih1, const float* __restrict__ bhh1,
    const float* __restrict__ Wdih, const float* __restrict__ Wdhh,
    const float* __restrict__ bdih, const float* __restrict__ bdhh,
    const float* __restrict__ Wo, const float* __restrict__ bo,
    float* __restrict__ out, __half* __restrict__ ys, __half* __restrict__ gi) {
  __shared__ SmemT s;
  const int tid = threadIdx.x;
  const int b = blockIdx.x;
  const int j = tid >> 1;      // output/gate row within H
  const int half = tid & 1;    // k-slice half
  const int k0 = half << 7;
  h32 wr0, wr1, wr2, wr3, wz0, wz1, wz2, wz3, wn0, wn1, wn2, wn3;  // 192 VGPRs, SSA
  float ar, az, an;

  // ---------------- Phase 1: encoder GRU layer 0 (input_size=1) ----------------
  s.xv[tid] = x[(size_t)b * LSEQ + tid];
  // NTHR=512 < 768 -> strided loop, NOT `if (tid<768)` (Round-0/1 NaN bug)
  for (int i = tid; i < 768; i += NTHR) {
    s.wih[i] = Wih0[i]; s.bih[i] = bih0[i]; s.bhh[i] = bhh0[i];
  }
  if (tid < 264) ((float*)s.h[0])[tid] = 0.f;
  LOADW(Whh0);
  __syncthreads();

  int pb = 0;
  for (int t = 0; t < LSEQ; ++t) {
    MATVEC(s.h[pb][half]);
    const float xt = s.xv[t];
    const float ghr = ar + s.bhh[j], ghz = az + s.bhh[j + 256], ghn = an + s.bhh[j + 512];
    const float r = sigm(fmaf(xt, s.wih[j], s.bih[j]) + ghr);
    const float z = sigm(fmaf(xt, s.wih[j + 256], s.bih[j + 256]) + ghz);
    const float n = tanh_(fmaf(r, ghn, fmaf(xt, s.wih[j + 512], s.bih[j + 512])));
    const float hold = s.h[pb][j >> 7][j & 127];
    const float hn = fmaf(z, hold - n, n);
    if (!half) {
      s.h[pb ^ 1][j >> 7][j & 127] = hn;
      ys[((size_t)b * LSEQ + t) * HDIM + j] = __float2half(hn);  // |h| < 1: f16-safe
    }
    pb ^= 1;
    __syncthreads();
  }

  // -------- Phase 2: GI1[t] = ys0[t] @ W_ih1.T + b_ih1 (no recurrence) --------
  LOADW(Wih1);
  for (int i = tid; i < 768; i += NTHR) s.bih[i] = bih1[i];
  if (tid < 128) {
    __half2 v = ((const __half2*)(ys + (size_t)b * LSEQ * HDIM))[tid];
    float2 f = __half22float2(v);
    s.stg[0][tid >> 6][(tid & 63) << 1] = f.x;
    s.stg[0][tid >> 6][((tid & 63) << 1) + 1] = f.y;
  }
  __syncthreads();
  for (int t = 0; t < LSEQ; ++t) {
    float2 nf;
    const bool ld = (t + 1 < LSEQ) && (tid < 128);
    if (ld) {
      __half2 v = ((const __half2*)(ys + ((size_t)b * LSEQ + t + 1) * HDIM))[tid];
      nf = __half22float2(v);
    }
    MATVEC(s.stg[t & 1][half]);
    if (!half) {
      const size_t o = ((size_t)b * LSEQ + t) * 768;
      gi[o + j] = __float2half(ar + s.bih[j]);
      gi[o + j + 256] = __float2half(az + s.bih[j + 256]);
      gi[o + j + 512] = __float2half(an + s.bih[j + 512]);
    }
    if (ld) {
      s.stg[(t + 1) & 1][tid >> 6][(tid & 63) << 1] = nf.x;
      s.stg[(t + 1) & 1][tid >> 6][((tid & 63) << 1) + 1] = nf.y;
    }
    __syncthreads();
  }

  // ---------------- Phase 3: encoder GRU layer 1 (uses precomputed GI) --------
  LOADW(Whh1);
  for (int i = tid; i < 768; i += NTHR) s.bhh[i] = bhh1[i];
  if (tid < 264) ((float*)s.h[0])[tid] = 0.f;
  __syncthreads();
  pb = 0;
  for (int t = 0; t < LSEQ; ++t) {
    const size_t o = ((size_t)b * LSEQ + t) * 768;
    const float gr = __half2float(gi[o + j]);           // prefetch before matvec;
    const float gz = __half2float(gi[o + j + 256]);     // latency hidden under fma_mix
    const float gn = __half2float(gi[o + j + 512]);
    MATVEC(s.h[pb][half]);
    const float ghr = ar + s.bhh[j], ghz = az + s.bhh[j + 256], ghn = an + s.bhh[j + 512];
    const float r = sigm(gr + ghr);
    const float z = sigm(gz + ghz);
    const float n = tanh_(fmaf(r, ghn, gn));
    const float hold = s.h[pb][j >> 7][j & 127];
    const float hn = fmaf(z, hold - n, n);
    if (!half) s.h[pb ^ 1][j >> 7][j & 127] = hn;
    pb ^= 1;
    __syncthreads();
  }

  // ---------------- Phase 4: autoregressive decoder (96 steps) ----------------
  LOADW(Wdhh);
  for (int i = tid; i < 768; i += NTHR) {
    s.wih[i] = Wdih[i]; s.bih[i] = bdih[i]; s.bhh[i] = bdhh[i];
  }
  if (tid < HDIM) s.wo[tid] = Wo[tid];
  if (tid == 0) s.inp = 0.f;
  const float bov = bo[0];
  __syncthreads();
  for (int t = 0; t < PRED; ++t) {
    const float it = s.inp;
    MATVEC(s.h[pb][half]);
    const float ghr = ar + s.bhh[j], ghz = az + s.bhh[j + 256], ghn = an + s.bhh[j + 512];
    const float r = sigm(fmaf(it, s.wih[j], s.bih[j]) + ghr);
    const float z = sigm(fmaf(it, s.wih[j + 256], s.bih[j + 256]) + ghz);
    const float n = tanh_(fmaf(r, ghn, fmaf(it, s.wih[j + 512], s.bih[j + 512])));
    const float hold = s.h[pb][j >> 7][j & 127];
    const float hn = fmaf(z, hold - n, n);
    float c = half ? 0.f : s.wo[j] * hn;
#pragma unroll
    for (int off = 1; off < 64; off <<= 1) c += __shfl_xor(c, off);
    if (!half) s.h[pb ^ 1][j >> 7][j & 127] = hn;
    if ((tid & 63) == 0) s.red[tid >> 6] = c;
    pb ^= 1;
    __syncthreads();
    if (tid == 0) {
      float ov = s.red[0] + s.red[1] + s.red[2] + s.red[3] +
                 s.red[4] + s.red[5] + s.red[6] + s.red[7] + bov;
      out[(size_t)b * PRED + t] = ov;
      s.inp = ov;
    }
    __syncthreads();
  }
}

extern "C" void kernel_launch(void* const* d_in, const int* in_sizes, int n_in,
                              void* d_out, int out_size, void* d_ws, size_t ws_size,
                              hipStream_t stream) {
  const float* x    = (const float*)d_in[0];
  const float* Wih0 = (const float*)d_in[1];
  const float* Whh0 = (const float*)d_in[2];
  const float* bih0 = (const float*)d_in[3];
  const float* bhh0 = (const float*)d_in[4];
  const float* Wih1 = (const float*)d_in[5];
  const float* Whh1 = (const float*)d_in[6];
  const float* bih1 = (const float*)d_in[7];
  const float* bhh1 = (const float*)d_in[8];
  const float* Wdih = (const float*)d_in[9];
  const float* Wdhh = (const float*)d_in[10];
  const float* bdih = (const float*)d_in[11];
  const float* bdhh = (const float*)d_in[12];
  const float* Wo   = (const float*)d_in[13];
  const float* bo   = (const float*)d_in[14];

  // ws layout: ys0 (f16, 256*512*256 = 64 MiB) | GI1 (f16, 256*512*768 = 192 MiB)
  __half* ys = (__half*)d_ws;
  __half* gi = ys + (size_t)256 * 512 * 256;

  gru_forecast<<<256, NTHR, 0, stream>>>(x, Wih0, Whh0, bih0, bhh0,
                                         Wih1, Whh1, bih1, bhh1,
                                         Wdih, Wdhh, bdih, bdhh, Wo, bo,
                                         (float*)d_out, ys, gi);
}

// Round 6
// 44462.720 us; speedup vs baseline: 1.6495x; 1.6023x over previous
//
#include <hip/hip_runtime.h>
#include <hip/hip_fp16.h>

#define HDIM 256
#define LSEQ 512
#define PRED 96
#define NTHR 1024

typedef _Float16 h16v __attribute__((ext_vector_type(16)));  // 16 f16 = 8 VGPRs, pure SSA

__device__ __forceinline__ float sigm(float x) { return 1.f / (1.f + __expf(-x)); }
// tanh(x) = 1 - 2/(e^{2x}+1); NaN-free at +/-inf
__device__ __forceinline__ float tanh_(float x) { float t = __expf(2.f * x); return 1.f - 2.f / (t + 1.f); }

struct SmemT {
  float h[2][4][68];    // [buf][quad][64 + pad4] fp32 hidden state; 68-float stride
                        // skews quad segments across banks (17 banks apart)
  float stg[2][4][68];  // phase-2 input staging, same layout
  float xv[LSEQ];
  float wih[768];       // rank-1 input weights for scalar-input phases
  float bih[768];
  float bhh[768];
  float wo[HDIM];
  float red[16];
  float inp;
};

// Fill one 16-wide f16 SSA vector from 16 consecutive fp32 (RN, same numerics as
// __float2half). Constant lane indices -> insertelement, no alloca, no SROA needed.
#define LOAD16(V, SRC)                                                             \
  {                                                                                \
    const float4* q4 = (const float4*)(SRC);                                       \
    _Pragma("unroll") for (int p = 0; p < 4; ++p) {                                \
      float4 f = q4[p];                                                            \
      (V)[4 * p + 0] = (_Float16)f.x; (V)[4 * p + 1] = (_Float16)f.y;              \
      (V)[4 * p + 2] = (_Float16)f.z; (V)[4 * p + 3] = (_Float16)f.w;              \
    }                                                                              \
  }

// This thread's 3 gate rows, 64-wide k-slice, of a [768][256] fp32 matrix ->
// 12 SSA f16 vectors = 96 VGPRs. 96 + ~25 temps fits the 128-VGPR cap the
// backend empirically grants (R2-R5: caps 64/128/128/128 — never 256).
#define LOADW(PTR)                                                                 \
  {                                                                                \
    const float* r0 = (PTR) + (size_t)j * HDIM + k0;                               \
    const float* r1 = (PTR) + (size_t)(j + 256) * HDIM + k0;                       \
    const float* r2 = (PTR) + (size_t)(j + 512) * HDIM + k0;                       \
    LOAD16(wr0, r0); LOAD16(wr1, r0 + 16); LOAD16(wr2, r0 + 32); LOAD16(wr3, r0 + 48); \
    LOAD16(wz0, r1); LOAD16(wz1, r1 + 16); LOAD16(wz2, r1 + 32); LOAD16(wz3, r1 + 48); \
    LOAD16(wn0, r2); LOAD16(wn1, r2 + 16); LOAD16(wn2, r2 + 32); LOAD16(wn3, r2 + 48); \
  }

// One 16-wide segment of the 3-gate dot. One LDS float4 read feeds all 3 gates.
// fmaf((float)f16, f32, f32) -> v_fma_mix_f32.
#define DOT16(Wr, Wz, Wn, H4)                                                      \
  {                                                                                \
    _Pragma("unroll") for (int p = 0; p < 4; ++p) {                                \
      float4 hv = (H4)[p];                                                         \
      ar = fmaf((float)(Wr)[4 * p + 0], hv.x, ar); ar = fmaf((float)(Wr)[4 * p + 1], hv.y, ar); \
      ar = fmaf((float)(Wr)[4 * p + 2], hv.z, ar); ar = fmaf((float)(Wr)[4 * p + 3], hv.w, ar); \
      az = fmaf((float)(Wz)[4 * p + 0], hv.x, az); az = fmaf((float)(Wz)[4 * p + 1], hv.y, az); \
      az = fmaf((float)(Wz)[4 * p + 2], hv.z, az); az = fmaf((float)(Wz)[4 * p + 3], hv.w, az); \
      an = fmaf((float)(Wn)[4 * p + 0], hv.x, an); an = fmaf((float)(Wn)[4 * p + 1], hv.y, an); \
      an = fmaf((float)(Wn)[4 * p + 2], hv.z, an); an = fmaf((float)(Wn)[4 * p + 3], hv.w, an); \
    }                                                                              \
  }

// 3-gate partial dot over this thread's 64-wide k-slice, then combine the 4 quads
// (lanes tid^1, tid^2 — same wave). Butterfly: ALL quad lanes end with the full sum.
#define MATVEC(HP)                                                                 \
  {                                                                                \
    ar = 0.f; az = 0.f; an = 0.f;                                                  \
    const float4* h4 = (const float4*)(HP);                                        \
    DOT16(wr0, wz0, wn0, h4);                                                      \
    DOT16(wr1, wz1, wn1, h4 + 4);                                                  \
    DOT16(wr2, wz2, wn2, h4 + 8);                                                  \
    DOT16(wr3, wz3, wn3, h4 + 12);                                                 \
    ar += __shfl_xor(ar, 1); ar += __shfl_xor(ar, 2);                              \
    az += __shfl_xor(az, 1); az += __shfl_xor(az, 2);                              \
    an += __shfl_xor(an, 1); an += __shfl_xor(an, 2);                              \
  }

// 1024 threads: weights = 96 VGPRs/thread (the ONLY layout where full residency
// fits the 128-VGPR cap; 512 thr would need 192). waves_per_eu(4,4): min=4 ->
// cap 512/4 = 128; max=4 stops the scheduler targeting 8/EU -> 64 (R2 pathology).
__global__ __attribute__((amdgpu_flat_work_group_size(NTHR, NTHR), amdgpu_waves_per_eu(4, 4)))
void gru_forecast(
    const float* __restrict__ x,
    const float* __restrict__ Wih0, const float* __restrict__ Whh0,
    const float* __restrict__ bih0, const float* __restrict__ bhh0,
    const float* __restrict__ Wih1, const float* __restrict__ Whh1,
    const float* __restrict__ bih1, const float* __restrict__ bhh1,
    const float* __restrict__ Wdih, const float* __restrict__ Wdhh,
    const float* __restrict__ bdih, const float* __restrict__ bdhh,
    const float* __restrict__ Wo, const float* __restrict__ bo,
    float* __restrict__ out, __half* __restrict__ ys, __half* __restrict__ gi) {
  __shared__ SmemT s;
  const int tid = threadIdx.x;
  const int b = blockIdx.x;
  const int j = tid >> 2;    // output/gate row within H (0..255)
  const int q = tid & 3;     // k-quad
  const int k0 = q << 6;
  h16v wr0, wr1, wr2, wr3, wz0, wz1, wz2, wz3, wn0, wn1, wn2, wn3;  // 96 VGPRs, SSA
  float ar, az, an;

  // ---------------- Phase 1: encoder GRU layer 0 (input_size=1) ----------------
  if (tid < LSEQ) s.xv[tid] = x[(size_t)b * LSEQ + tid];
  if (tid < 768) { s.wih[tid] = Wih0[tid]; s.bih[tid] = bih0[tid]; s.bhh[tid] = bhh0[tid]; }
  if (tid < 272) ((float*)s.h[0])[tid] = 0.f;
  LOADW(Whh0);
  __syncthreads();

  int pb = 0;
  for (int t = 0; t < LSEQ; ++t) {
    MATVEC(s.h[pb][q]);
    const float xt = s.xv[t];
    const float ghr = ar + s.bhh[j], ghz = az + s.bhh[j + 256], ghn = an + s.bhh[j + 512];
    const float r = sigm(fmaf(xt, s.wih[j], s.bih[j]) + ghr);
    const float z = sigm(fmaf(xt, s.wih[j + 256], s.bih[j + 256]) + ghz);
    const float n = tanh_(fmaf(r, ghn, fmaf(xt, s.wih[j + 512], s.bih[j + 512])));
    const float hold = s.h[pb][j >> 6][j & 63];
    const float hn = fmaf(z, hold - n, n);
    if (q == 0) {
      s.h[pb ^ 1][j >> 6][j & 63] = hn;
      ys[((size_t)b * LSEQ + t) * HDIM + j] = __float2half(hn);  // |h| < 1: f16-safe
    }
    pb ^= 1;
    __syncthreads();
  }

  // -------- Phase 2: GI1[t] = ys0[t] @ W_ih1.T + b_ih1 (no recurrence) --------
  LOADW(Wih1);
  if (tid < 768) s.bih[tid] = bih1[tid];
  if (tid < 128) {
    __half2 v = ((const __half2*)(ys + (size_t)b * LSEQ * HDIM))[tid];
    float2 f = __half22float2(v);
    s.stg[0][tid >> 5][(tid & 31) << 1] = f.x;
    s.stg[0][tid >> 5][((tid & 31) << 1) + 1] = f.y;
  }
  __syncthreads();
  for (int t = 0; t < LSEQ; ++t) {
    float2 nf;
    const bool ld = (t + 1 < LSEQ) && (tid < 128);
    if (ld) {
      __half2 v = ((const __half2*)(ys + ((size_t)b * LSEQ + t + 1) * HDIM))[tid];
      nf = __half22float2(v);
    }
    MATVEC(s.stg[t & 1][q]);
    // butterfly gave every quad lane the full sums: spread the 3 stores across quads
    const size_t o = ((size_t)b * LSEQ + t) * 768;
    if (q == 0) gi[o + j] = __float2half(ar + s.bih[j]);
    else if (q == 1) gi[o + j + 256] = __float2half(az + s.bih[j + 256]);
    else if (q == 2) gi[o + j + 512] = __float2half(an + s.bih[j + 512]);
    if (ld) {
      s.stg[(t + 1) & 1][tid >> 5][(tid & 31) << 1] = nf.x;
      s.stg[(t + 1) & 1][tid >> 5][((tid & 31) << 1) + 1] = nf.y;
    }
    __syncthreads();
  }

  // ---------------- Phase 3: encoder GRU layer 1 (uses precomputed GI) --------
  LOADW(Whh1);
  if (tid < 768) s.bhh[tid] = bhh1[tid];
  if (tid < 272) ((float*)s.h[0])[tid] = 0.f;
  __syncthreads();
  pb = 0;
  for (int t = 0; t < LSEQ; ++t) {
    const size_t o = ((size_t)b * LSEQ + t) * 768;
    const float gr = __half2float(gi[o + j]);           // prefetch before matvec;
    const float gz = __half2float(gi[o + j + 256]);     // latency hidden under fma_mix
    const float gn = __half2float(gi[o + j + 512]);
    MATVEC(s.h[pb][q]);
    const float ghr = ar + s.bhh[j], ghz = az + s.bhh[j + 256], ghn = an + s.bhh[j + 512];
    const float r = sigm(gr + ghr);
    const float z = sigm(gz + ghz);
    const float n = tanh_(fmaf(r, ghn, gn));
    const float hold = s.h[pb][j >> 6][j & 63];
    const float hn = fmaf(z, hold - n, n);
    if (q == 0) s.h[pb ^ 1][j >> 6][j & 63] = hn;
    pb ^= 1;
    __syncthreads();
  }

  // ---------------- Phase 4: autoregressive decoder (96 steps) ----------------
  LOADW(Wdhh);
  if (tid < 768) { s.wih[tid] = Wdih[tid]; s.bih[tid] = bdih[tid]; s.bhh[tid] = bdhh[tid]; }
  if (tid < HDIM) s.wo[tid] = Wo[tid];
  if (tid == 0) s.inp = 0.f;
  const float bov = bo[0];
  __syncthreads();
  for (int t = 0; t < PRED; ++t) {
    const float it = s.inp;
    MATVEC(s.h[pb][q]);
    const float ghr = ar + s.bhh[j], ghz = az + s.bhh[j + 256], ghn = an + s.bhh[j + 512];
    const float r = sigm(fmaf(it, s.wih[j], s.bih[j]) + ghr);
    const float z = sigm(fmaf(it, s.wih[j + 256], s.bih[j + 256]) + ghz);
    const float n = tanh_(fmaf(r, ghn, fmaf(it, s.wih[j + 512], s.bih[j + 512])));
    const float hold = s.h[pb][j >> 6][j & 63];
    const float hn = fmaf(z, hold - n, n);
    float c = (q == 0) ? s.wo[j] * hn : 0.f;
#pragma unroll
    for (int off = 1; off < 64; off <<= 1) c += __shfl_xor(c, off);
    if (q == 0) s.h[pb ^ 1][j >> 6][j & 63] = hn;
    if ((tid & 63) == 0) s.red[tid >> 6] = c;
    pb ^= 1;
    __syncthreads();
    if (tid == 0) {
      float ov = bov;
#pragma unroll
      for (int i2 = 0; i2 < 16; ++i2) ov += s.red[i2];
      out[(size_t)b * PRED + t] = ov;
      s.inp = ov;
    }
    __syncthreads();
  }
}

extern "C" void kernel_launch(void* const* d_in, const int* in_sizes, int n_in,
                              void* d_out, int out_size, void* d_ws, size_t ws_size,
                              hipStream_t stream) {
  const float* x    = (const float*)d_in[0];
  const float* Wih0 = (const float*)d_in[1];
  const float* Whh0 = (const float*)d_in[2];
  const float* bih0 = (const float*)d_in[3];
  const float* bhh0 = (const float*)d_in[4];
  const float* Wih1 = (const float*)d_in[5];
  const float* Whh1 = (const float*)d_in[6];
  const float* bih1 = (const float*)d_in[7];
  const float* bhh1 = (const float*)d_in[8];
  const float* Wdih = (const float*)d_in[9];
  const float* Wdhh = (const float*)d_in[10];
  const float* bdih = (const float*)d_in[11];
  const float* bdhh = (const float*)d_in[12];
  const float* Wo   = (const float*)d_in[13];
  const float* bo   = (const float*)d_in[14];

  // ws layout: ys0 (f16, 256*512*256 = 64 MiB) | GI1 (f16, 256*512*768 = 192 MiB)
  __half* ys = (__half*)d_ws;
  __half* gi = ys + (size_t)256 * 512 * 256;

  gru_forecast<<<256, NTHR, 0, stream>>>(x, Wih0, Whh0, bih0, bhh0,
                                         Wih1, Whh1, bih1, bhh1,
                                         Wdih, Wdhh, bdih, bdhh, Wo, bo,
                                         (float*)d_out, ys, gi);
}

// Round 7
// 10886.184 us; speedup vs baseline: 6.7372x; 4.0843x over previous
//
#include <hip/hip_runtime.h>
#include <hip/hip_fp16.h>

#define HDIM 256
#define LSEQ 512
#define PRED 96
#define NTHR 1024

typedef _Float16 h16v __attribute__((ext_vector_type(16)));  // 16 f16 = 8 VGPRs, SSA
typedef _Float16 h2t  __attribute__((ext_vector_type(2)));

__device__ __forceinline__ float sigm(float x) { return 1.f / (1.f + __expf(-x)); }
// tanh(x) = 1 - 2/(e^{2x}+1); NaN-free at +/-inf
__device__ __forceinline__ float tanh_(float x) { float t = __expf(2.f * x); return 1.f - 2.f / (t + 1.f); }

struct SmemT {
  float h[2][4][68];    // [buf][quad][64 + pad4]; 68-float stride -> quad bases 17 banks
                        // apart -> 4 broadcast groups on disjoint banks
  float stg[2][4][68];  // phase-2 input staging, same layout
  float xv[LSEQ];
  float wih[768];       // rank-1 input weights for scalar-input phases
  float bih[768];
  float bhh[768];
  float wo[HDIM];
  float red[16];
  float inp;
};

// ---- AGPR plumbing ----------------------------------------------------------
// Allocator law (R2-R6): arch-VGPR grant = 256 / max(min_waves_per_eu,
// ceil(block_waves/4)) — the OTHER half of the unified RF (AGPRs) is never
// granted to HIP code. Claim it with explicit accvgpr asm. Writes are
// non-volatile (dataflow keeps them); reads are volatile so the compiler can
// neither CSE nor hoist 64 values into arch regs across the step loop.
#define AW(A, X, Y)                                                                \
  { __half2 _h = __floats2half2_rn((X), (Y));                                      \
    unsigned int _u = __builtin_bit_cast(unsigned int, _h);                        \
    asm("v_accvgpr_write_b32 %0, %1" : "=a"(A) : "v"(_u)); }
#define AWP(A, F2) AW(A, (F2).x, (F2).y)

// read one AGPR (2 f16), feed 2 mixed-precision fmas: fmaf((float)f16,f32,f32)
// -> v_fma_mix_f32
#define AFMA(ACC, A, HX, HY)                                                       \
  { unsigned int _t;                                                               \
    asm volatile("v_accvgpr_read_b32 %0, %1" : "=v"(_t) : "a"(A));                 \
    h2t _w = __builtin_bit_cast(h2t, _t);                                          \
    ACC = fmaf((float)_w[0], (HX), ACC);                                           \
    ACC = fmaf((float)_w[1], (HY), ACC); }

// Fill one 16-wide f16 SSA vector from 16 consecutive fp32 (RN).
#define LOAD16(V, SRC)                                                             \
  {                                                                                \
    const float4* q4 = (const float4*)(SRC);                                       \
    _Pragma("unroll") for (int p = 0; p < 4; ++p) {                                \
      float4 f = q4[p];                                                            \
      (V)[4 * p + 0] = (_Float16)f.x; (V)[4 * p + 1] = (_Float16)f.y;              \
      (V)[4 * p + 2] = (_Float16)f.z; (V)[4 * p + 3] = (_Float16)f.w;              \
    }                                                                              \
  }

// This thread's 3 gate rows (64-wide k-slice) of a [768][256] fp32 matrix:
// r-gate -> 4 arch SSA vectors (32 VGPRs); z,n gates -> 64 AGPRs (a-pair = 2 f16).
#define LOADW(PTR)                                                                 \
  {                                                                                \
    const float* r0 = (PTR) + (size_t)j * HDIM + k0;                               \
    LOAD16(wr0, r0); LOAD16(wr1, r0 + 16); LOAD16(wr2, r0 + 32); LOAD16(wr3, r0 + 48); \
    const float2* z2 = (const float2*)((PTR) + (size_t)(j + 256) * HDIM + k0);     \
    const float2* n2 = (const float2*)((PTR) + (size_t)(j + 512) * HDIM + k0);     \
    AWP(az00,z2[0])  AWP(az01,z2[1])  AWP(az02,z2[2])  AWP(az03,z2[3])             \
    AWP(az04,z2[4])  AWP(az05,z2[5])  AWP(az06,z2[6])  AWP(az07,z2[7])             \
    AWP(az08,z2[8])  AWP(az09,z2[9])  AWP(az10,z2[10]) AWP(az11,z2[11])            \
    AWP(az12,z2[12]) AWP(az13,z2[13]) AWP(az14,z2[14]) AWP(az15,z2[15])            \
    AWP(az16,z2[16]) AWP(az17,z2[17]) AWP(az18,z2[18]) AWP(az19,z2[19])            \
    AWP(az20,z2[20]) AWP(az21,z2[21]) AWP(az22,z2[22]) AWP(az23,z2[23])            \
    AWP(az24,z2[24]) AWP(az25,z2[25]) AWP(az26,z2[26]) AWP(az27,z2[27])            \
    AWP(az28,z2[28]) AWP(az29,z2[29]) AWP(az30,z2[30]) AWP(az31,z2[31])            \
    AWP(an00,n2[0])  AWP(an01,n2[1])  AWP(an02,n2[2])  AWP(an03,n2[3])             \
    AWP(an04,n2[4])  AWP(an05,n2[5])  AWP(an06,n2[6])  AWP(an07,n2[7])             \
    AWP(an08,n2[8])  AWP(an09,n2[9])  AWP(an10,n2[10]) AWP(an11,n2[11])            \
    AWP(an12,n2[12]) AWP(an13,n2[13]) AWP(an14,n2[14]) AWP(an15,n2[15])            \
    AWP(an16,n2[16]) AWP(an17,n2[17]) AWP(an18,n2[18]) AWP(an19,n2[19])            \
    AWP(an20,n2[20]) AWP(an21,n2[21]) AWP(an22,n2[22]) AWP(an23,n2[23])            \
    AWP(an24,n2[24]) AWP(an25,n2[25]) AWP(an26,n2[26]) AWP(an27,n2[27])            \
    AWP(an28,n2[28]) AWP(an29,n2[29]) AWP(an30,n2[30]) AWP(an31,n2[31])            \
  }

// One float4 of h: 4 r-fmas from arch vector WR at lane L, plus z/n from AGPRs.
#define MSTEP(P, WR, L, AZ0, AZ1, AN0, AN1)                                        \
  { float4 hv = h4[P];                                                             \
    ar = fmaf((float)WR[(L)+0], hv.x, ar); ar = fmaf((float)WR[(L)+1], hv.y, ar);  \
    ar = fmaf((float)WR[(L)+2], hv.z, ar); ar = fmaf((float)WR[(L)+3], hv.w, ar);  \
    AFMA(az, AZ0, hv.x, hv.y) AFMA(az, AZ1, hv.z, hv.w)                            \
    AFMA(an, AN0, hv.x, hv.y) AFMA(an, AN1, hv.z, hv.w) }

// 3-gate partial dot over this thread's 64-wide k-slice, then quad butterfly
// (lanes tid^1, tid^2 — same wave): all quad lanes end with the full sums.
#define MATVEC(HP)                                                                 \
  {                                                                                \
    ar = 0.f; az = 0.f; an = 0.f;                                                  \
    const float4* h4 = (const float4*)(HP);                                        \
    MSTEP(0,  wr0, 0,  az00, az01, an00, an01)                                     \
    MSTEP(1,  wr0, 4,  az02, az03, an02, an03)                                     \
    MSTEP(2,  wr0, 8,  az04, az05, an04, an05)                                     \
    MSTEP(3,  wr0, 12, az06, az07, an06, an07)                                     \
    MSTEP(4,  wr1, 0,  az08, az09, an08, an09)                                     \
    MSTEP(5,  wr1, 4,  az10, az11, an10, an11)                                     \
    MSTEP(6,  wr1, 8,  az12, az13, an12, an13)                                     \
    MSTEP(7,  wr1, 12, az14, az15, an14, an15)                                     \
    MSTEP(8,  wr2, 0,  az16, az17, an16, an17)                                     \
    MSTEP(9,  wr2, 4,  az18, az19, an18, an19)                                     \
    MSTEP(10, wr2, 8,  az20, az21, an20, an21)                                     \
    MSTEP(11, wr2, 12, az22, az23, an22, an23)                                     \
    MSTEP(12, wr3, 0,  az24, az25, an24, an25)                                     \
    MSTEP(13, wr3, 4,  az26, az27, an26, an27)                                     \
    MSTEP(14, wr3, 8,  az28, az29, an28, an29)                                     \
    MSTEP(15, wr3, 12, az30, az31, an30, an31)                                     \
    ar += __shfl_xor(ar, 1); ar += __shfl_xor(ar, 2);                              \
    az += __shfl_xor(az, 1); az += __shfl_xor(az, 2);                              \
    an += __shfl_xor(an, 1); an += __shfl_xor(an, 2);                              \
  }

__global__ __attribute__((amdgpu_flat_work_group_size(NTHR, NTHR), amdgpu_waves_per_eu(4, 4)))
void gru_forecast(
    const float* __restrict__ x,
    const float* __restrict__ Wih0, const float* __restrict__ Whh0,
    const float* __restrict__ bih0, const float* __restrict__ bhh0,
    const float* __restrict__ Wih1, const float* __restrict__ Whh1,
    const float* __restrict__ bih1, const float* __restrict__ bhh1,
    const float* __restrict__ Wdih, const float* __restrict__ Wdhh,
    const float* __restrict__ bdih, const float* __restrict__ bdhh,
    const float* __restrict__ Wo, const float* __restrict__ bo,
    float* __restrict__ out, __half* __restrict__ ys, __half* __restrict__ gi) {
  __shared__ SmemT s;
  const int tid = threadIdx.x;
  const int b = blockIdx.x;
  const int j = tid >> 2;    // output/gate row within H (0..255)
  const int q = tid & 3;     // k-quad
  const int k0 = q << 6;
  h16v wr0, wr1, wr2, wr3;   // r-gate slice: 32 arch VGPRs (fits the 64-reg grant)
  unsigned int                // z/n-gate slices: 64 AGPRs (the unclaimed half-RF)
      az00,az01,az02,az03,az04,az05,az06,az07,az08,az09,az10,az11,az12,az13,az14,az15,
      az16,az17,az18,az19,az20,az21,az22,az23,az24,az25,az26,az27,az28,az29,az30,az31,
      an00,an01,an02,an03,an04,an05,an06,an07,an08,an09,an10,an11,an12,an13,an14,an15,
      an16,an17,an18,an19,an20,an21,an22,an23,an24,an25,an26,an27,an28,an29,an30,an31;
  float ar, az, an;

  // ---------------- Phase 1: encoder GRU layer 0 (input_size=1) ----------------
  if (tid < LSEQ) s.xv[tid] = x[(size_t)b * LSEQ + tid];
  if (tid < 768) { s.wih[tid] = Wih0[tid]; s.bih[tid] = bih0[tid]; s.bhh[tid] = bhh0[tid]; }
  if (tid < 272) ((float*)s.h[0])[tid] = 0.f;
  LOADW(Whh0);
  __syncthreads();

  int pb = 0;
  for (int t = 0; t < LSEQ; ++t) {
    MATVEC(s.h[pb][q]);
    const float xt = s.xv[t];
    const float ghr = ar + s.bhh[j], ghz = az + s.bhh[j + 256], ghn = an + s.bhh[j + 512];
    const float r = sigm(fmaf(xt, s.wih[j], s.bih[j]) + ghr);
    const float z = sigm(fmaf(xt, s.wih[j + 256], s.bih[j + 256]) + ghz);
    const float n = tanh_(fmaf(r, ghn, fmaf(xt, s.wih[j + 512], s.bih[j + 512])));
    const float hold = s.h[pb][j >> 6][j & 63];
    const float hn = fmaf(z, hold - n, n);
    if (q == 0) {
      s.h[pb ^ 1][j >> 6][j & 63] = hn;
      ys[((size_t)b * LSEQ + t) * HDIM + j] = __float2half(hn);  // |h| < 1: f16-safe
    }
    pb ^= 1;
    __syncthreads();
  }

  // -------- Phase 2: GI1[t] = ys0[t] @ W_ih1.T + b_ih1 (no recurrence) --------
  LOADW(Wih1);
  if (tid < 768) s.bih[tid] = bih1[tid];
  if (tid < 128) {
    __half2 v = ((const __half2*)(ys + (size_t)b * LSEQ * HDIM))[tid];
    float2 f = __half22float2(v);
    s.stg[0][tid >> 5][(tid & 31) << 1] = f.x;
    s.stg[0][tid >> 5][((tid & 31) << 1) + 1] = f.y;
  }
  __syncthreads();
  for (int t = 0; t < LSEQ; ++t) {
    float2 nf;
    const bool ld = (t + 1 < LSEQ) && (tid < 128);
    if (ld) {
      __half2 v = ((const __half2*)(ys + ((size_t)b * LSEQ + t + 1) * HDIM))[tid];
      nf = __half22float2(v);
    }
    MATVEC(s.stg[t & 1][q]);
    // butterfly gave every quad lane the full sums: spread the 3 stores across quads
    const size_t o = ((size_t)b * LSEQ + t) * 768;
    if (q == 0) gi[o + j] = __float2half(ar + s.bih[j]);
    else if (q == 1) gi[o + j + 256] = __float2half(az + s.bih[j + 256]);
    else if (q == 2) gi[o + j + 512] = __float2half(an + s.bih[j + 512]);
    if (ld) {
      s.stg[(t + 1) & 1][tid >> 5][(tid & 31) << 1] = nf.x;
      s.stg[(t + 1) & 1][tid >> 5][((tid & 31) << 1) + 1] = nf.y;
    }
    __syncthreads();
  }

  // ---------------- Phase 3: encoder GRU layer 1 (uses precomputed GI) --------
  LOADW(Whh1);
  if (tid < 768) s.bhh[tid] = bhh1[tid];
  if (tid < 272) ((float*)s.h[0])[tid] = 0.f;
  __syncthreads();
  pb = 0;
  for (int t = 0; t < LSEQ; ++t) {
    const size_t o = ((size_t)b * LSEQ + t) * 768;
    const float gr = __half2float(gi[o + j]);           // prefetch before matvec;
    const float gz = __half2float(gi[o + j + 256]);     // latency hidden under fma_mix
    const float gn = __half2float(gi[o + j + 512]);
    MATVEC(s.h[pb][q]);
    const float ghr = ar + s.bhh[j], ghz = az + s.bhh[j + 256], ghn = an + s.bhh[j + 512];
    const float r = sigm(gr + ghr);
    const float z = sigm(gz + ghz);
    const float n = tanh_(fmaf(r, ghn, gn));
    const float hold = s.h[pb][j >> 6][j & 63];
    const float hn = fmaf(z, hold - n, n);
    if (q == 0) s.h[pb ^ 1][j >> 6][j & 63] = hn;
    pb ^= 1;
    __syncthreads();
  }

  // ---------------- Phase 4: autoregressive decoder (96 steps) ----------------
  LOADW(Wdhh);
  if (tid < 768) { s.wih[tid] = Wdih[tid]; s.bih[tid] = bdih[tid]; s.bhh[tid] = bdhh[tid]; }
  if (tid < HDIM) s.wo[tid] = Wo[tid];
  if (tid == 0) s.inp = 0.f;
  const float bov = bo[0];
  __syncthreads();
  for (int t = 0; t < PRED; ++t) {
    const float it = s.inp;
    MATVEC(s.h[pb][q]);
    const float ghr = ar + s.bhh[j], ghz = az + s.bhh[j + 256], ghn = an + s.bhh[j + 512];
    const float r = sigm(fmaf(it, s.wih[j], s.bih[j]) + ghr);
    const float z = sigm(fmaf(it, s.wih[j + 256], s.bih[j + 256]) + ghz);
    const float n = tanh_(fmaf(r, ghn, fmaf(it, s.wih[j + 512], s.bih[j + 512])));
    const float hold = s.h[pb][j >> 6][j & 63];
    const float hn = fmaf(z, hold - n, n);
    float c = (q == 0) ? s.wo[j] * hn : 0.f;
#pragma unroll
    for (int off = 1; off < 64; off <<= 1) c += __shfl_xor(c, off);
    if (q == 0) s.h[pb ^ 1][j >> 6][j & 63] = hn;
    if ((tid & 63) == 0) s.red[tid >> 6] = c;
    pb ^= 1;
    __syncthreads();
    if (tid == 0) {
      float ov = bov;
#pragma unroll
      for (int i2 = 0; i2 < 16; ++i2) ov += s.red[i2];
      out[(size_t)b * PRED + t] = ov;
      s.inp = ov;
    }
    __syncthreads();
  }
}

extern "C" void kernel_launch(void* const* d_in, const int* in_sizes, int n_in,
                              void* d_out, int out_size, void* d_ws, size_t ws_size,
                              hipStream_t stream) {
  const float* x    = (const float*)d_in[0];
  const float* Wih0 = (const float*)d_in[1];
  const float* Whh0 = (const float*)d_in[2];
  const float* bih0 = (const float*)d_in[3];
  const float* bhh0 = (const float*)d_in[4];
  const float* Wih1 = (const float*)d_in[5];
  const float* Whh1 = (const float*)d_in[6];
  const float* bih1 = (const float*)d_in[7];
  const float* bhh1 = (const float*)d_in[8];
  const float* Wdih = (const float*)d_in[9];
  const float* Wdhh = (const float*)d_in[10];
  const float* bdih = (const float*)d_in[11];
  const float* bdhh = (const float*)d_in[12];
  const float* Wo   = (const float*)d_in[13];
  const float* bo   = (const float*)d_in[14];

  // ws layout: ys0 (f16, 256*512*256 = 64 MiB) | GI1 (f16, 256*512*768 = 192 MiB)
  __half* ys = (__half*)d_ws;
  __half* gi = ys + (size_t)256 * 512 * 256;

  gru_forecast<<<256, NTHR, 0, stream>>>(x, Wih0, Whh0, bih0, bhh0,
                                         Wih1, Whh1, bih1, bhh1,
                                         Wdih, Wdhh, bdih, bdhh, Wo, bo,
                                         (float*)d_out, ys, gi);
}

// Round 9
// 5145.575 us; speedup vs baseline: 14.2534x; 2.1156x over previous
//
#include <hip/hip_runtime.h>
#include <hip/hip_fp16.h>

#define HDIM 256
#define LSEQ 512
#define PRED 96
#define NTHR 1024

__device__ __forceinline__ float sigm(float x) { return 1.f / (1.f + __expf(-x)); }
__device__ __forceinline__ float tanh_(float x) { float t = __expf(2.f * x); return 1.f - 2.f / (t + 1.f); }

// quad butterfly (lanes xor 1, xor 2) via DPP quad_perm — pure VALU, no LDS pipe.
__device__ __forceinline__ float qred(float v) {
  v += __builtin_bit_cast(float, __builtin_amdgcn_update_dpp(
           0, __builtin_bit_cast(int, v), 0xB1, 0xF, 0xF, true));  // quad_perm [1,0,3,2]
  v += __builtin_bit_cast(float, __builtin_amdgcn_update_dpp(
           0, __builtin_bit_cast(int, v), 0x4E, 0xF, 0xF, true));  // quad_perm [2,3,0,1]
  return v;
}

struct SmemT {
  float h[2][4][68];  // [buf][quad][64+pad4]; 68-float stride -> quad bases 17 banks apart
  float xv[LSEQ];
  float wih[768];     // rank-1 input weights for scalar-input phases
  float bih[768];
  float bhh[768];
  float wo[HDIM];
  float red[16];
  float inp;
};

// pack 2 fp32 -> 1 u32 of 2 f16 (RN) — arch-resident weight pair
#define WPK(D, X, Y)                                                               \
  { __half2 _h = __floats2half2_rn((X), (Y));                                      \
    (D) = __builtin_bit_cast(unsigned int, _h); }

// AGPR write (R7-proven): claims the acc half of the unified RF
#define AW(A, X, Y)                                                                \
  { __half2 _h = __floats2half2_rn((X), (Y));                                      \
    unsigned int _u = __builtin_bit_cast(unsigned int, _h);                        \
    asm("v_accvgpr_write_b32 %0, %1" : "=a"(A) : "v"(_u)); }
#define AWP(A, F2) AW(A, (F2).x, (F2).y)

// 2 MACs from an arch packed pair (f16 lo,hi) x f32 h — exactly 2 v_fma_mix_f32
#define FMA2V(ACC, WP, HX, HY)                                                     \
  asm("v_fma_mix_f32 %0, %1, %2, %0 op_sel:[0,0,0] op_sel_hi:[1,0,0]\n\t"          \
      "v_fma_mix_f32 %0, %1, %3, %0 op_sel:[1,0,0] op_sel_hi:[1,0,0]"              \
      : "+v"(ACC) : "v"(WP), "v"(HX), "v"(HY));

// 2 MACs from an AGPR pair x f32 h — read + 2 mixes, one non-volatile block
#define FMA2A(ACC, AW_, HX, HY)                                                    \
  { unsigned int _t;                                                               \
    asm("v_accvgpr_read_b32 %1, %2\n\t"                                            \
        "v_fma_mix_f32 %0, %1, %3, %0 op_sel:[0,0,0] op_sel_hi:[1,0,0]\n\t"        \
        "v_fma_mix_f32 %0, %1, %4, %0 op_sel:[1,0,0] op_sel_hi:[1,0,0]"            \
        : "+v"(ACC), "=&v"(_t) : "a"(AW_), "v"(HX), "v"(HY)); }

// 2 MACs, both operands f16 pairs (phase 2: w f16 x ys f16; fma_mix widens to f32
// internally — bit-identical to f16xf32 path on the same values)
#define FMA2VH(ACC, WP, YP)                                                        \
  asm("v_fma_mix_f32 %0, %1, %2, %0 op_sel:[0,0,0] op_sel_hi:[1,1,0]\n\t"          \
      "v_fma_mix_f32 %0, %1, %2, %0 op_sel:[1,1,0] op_sel_hi:[1,1,0]"              \
      : "+v"(ACC) : "v"(WP), "v"(YP));
#define FMA2AH(ACC, AW_, YP)                                                       \
  { unsigned int _t;                                                               \
    asm("v_accvgpr_read_b32 %1, %2\n\t"                                            \
        "v_fma_mix_f32 %0, %1, %3, %0 op_sel:[0,0,0] op_sel_hi:[1,1,0]\n\t"        \
        "v_fma_mix_f32 %0, %1, %3, %0 op_sel:[1,1,0] op_sel_hi:[1,1,0]"            \
        : "+v"(ACC), "=&v"(_t) : "a"(AW_), "v"(YP)); }

// This thread's 3 gate rows (64-wide k-slice) of [768][256] fp32:
// r -> 32 arch u32 pairs; z,n -> 64 AGPR pairs.
#define LOADW(PTR)                                                                 \
  {                                                                                \
    const float4* r4 = (const float4*)((PTR) + (size_t)j * HDIM + k0);             \
    float4 f;                                                                      \
    f=r4[0];  WPK(wp00,f.x,f.y) WPK(wp01,f.z,f.w)                                  \
    f=r4[1];  WPK(wp02,f.x,f.y) WPK(wp03,f.z,f.w)                                  \
    f=r4[2];  WPK(wp04,f.x,f.y) WPK(wp05,f.z,f.w)                                  \
    f=r4[3];  WPK(wp06,f.x,f.y) WPK(wp07,f.z,f.w)                                  \
    f=r4[4];  WPK(wp08,f.x,f.y) WPK(wp09,f.z,f.w)                                  \
    f=r4[5];  WPK(wp10,f.x,f.y) WPK(wp11,f.z,f.w)                                  \
    f=r4[6];  WPK(wp12,f.x,f.y) WPK(wp13,f.z,f.w)                                  \
    f=r4[7];  WPK(wp14,f.x,f.y) WPK(wp15,f.z,f.w)                                  \
    f=r4[8];  WPK(wp16,f.x,f.y) WPK(wp17,f.z,f.w)                                  \
    f=r4[9];  WPK(wp18,f.x,f.y) WPK(wp19,f.z,f.w)                                  \
    f=r4[10]; WPK(wp20,f.x,f.y) WPK(wp21,f.z,f.w)                                  \
    f=r4[11]; WPK(wp22,f.x,f.y) WPK(wp23,f.z,f.w)                                  \
    f=r4[12]; WPK(wp24,f.x,f.y) WPK(wp25,f.z,f.w)                                  \
    f=r4[13]; WPK(wp26,f.x,f.y) WPK(wp27,f.z,f.w)                                  \
    f=r4[14]; WPK(wp28,f.x,f.y) WPK(wp29,f.z,f.w)                                  \
    f=r4[15]; WPK(wp30,f.x,f.y) WPK(wp31,f.z,f.w)                                  \
    const float2* z2 = (const float2*)((PTR) + (size_t)(j + 256) * HDIM + k0);     \
    const float2* n2 = (const float2*)((PTR) + (size_t)(j + 512) * HDIM + k0);     \
    AWP(az00,z2[0])  AWP(az01,z2[1])  AWP(az02,z2[2])  AWP(az03,z2[3])             \
    AWP(az04,z2[4])  AWP(az05,z2[5])  AWP(az06,z2[6])  AWP(az07,z2[7])             \
    AWP(az08,z2[8])  AWP(az09,z2[9])  AWP(az10,z2[10]) AWP(az11,z2[11])            \
    AWP(az12,z2[12]) AWP(az13,z2[13]) AWP(az14,z2[14]) AWP(az15,z2[15])            \
    AWP(az16,z2[16]) AWP(az17,z2[17]) AWP(az18,z2[18]) AWP(az19,z2[19])            \
    AWP(az20,z2[20]) AWP(az21,z2[21]) AWP(az22,z2[22]) AWP(az23,z2[23])            \
    AWP(az24,z2[24]) AWP(az25,z2[25]) AWP(az26,z2[26]) AWP(az27,z2[27])            \
    AWP(az28,z2[28]) AWP(az29,z2[29]) AWP(az30,z2[30]) AWP(az31,z2[31])            \
    AWP(an00,n2[0])  AWP(an01,n2[1])  AWP(an02,n2[2])  AWP(an03,n2[3])             \
    AWP(an04,n2[4])  AWP(an05,n2[5])  AWP(an06,n2[6])  AWP(an07,n2[7])             \
    AWP(an08,n2[8])  AWP(an09,n2[9])  AWP(an10,n2[10]) AWP(an11,n2[11])            \
    AWP(an12,n2[12]) AWP(an13,n2[13]) AWP(an14,n2[14]) AWP(an15,n2[15])            \
    AWP(an16,n2[16]) AWP(an17,n2[17]) AWP(an18,n2[18]) AWP(an19,n2[19])            \
    AWP(an20,n2[20]) AWP(an21,n2[21]) AWP(an22,n2[22]) AWP(an23,n2[23])            \
    AWP(an24,n2[24]) AWP(an25,n2[25]) AWP(an26,n2[26]) AWP(an27,n2[27])            \
    AWP(an28,n2[28]) AWP(an29,n2[29]) AWP(an30,n2[30]) AWP(an31,n2[31])            \
  }

// one float4 of h feeds 12 MACs (4 k x 3 gates): 12 fma_mix + 4 accvgpr_read
#define MCH(P, WA, WB, ZA, ZB, NA, NB)                                             \
  { float4 hv = h4[P];                                                             \
    FMA2V(ar, WA, hv.x, hv.y) FMA2V(ar, WB, hv.z, hv.w)                            \
    FMA2A(az, ZA, hv.x, hv.y) FMA2A(az, ZB, hv.z, hv.w)                            \
    FMA2A(an, NA, hv.x, hv.y) FMA2A(an, NB, hv.z, hv.w) }

#define MATVEC(HP)                                                                 \
  { ar = 0.f; az = 0.f; an = 0.f;                                                  \
    const float4* h4 = (const float4*)(HP);                                        \
    MCH(0,  wp00, wp01, az00, az01, an00, an01)                                    \
    MCH(1,  wp02, wp03, az02, az03, an02, an03)                                    \
    MCH(2,  wp04, wp05, az04, az05, an04, an05)                                    \
    MCH(3,  wp06, wp07, az06, az07, an06, an07)                                    \
    MCH(4,  wp08, wp09, az08, az09, an08, an09)                                    \
    MCH(5,  wp10, wp11, az10, az11, an10, an11)                                    \
    MCH(6,  wp12, wp13, az12, az13, an12, an13)                                    \
    MCH(7,  wp14, wp15, az14, az15, an14, an15)                                    \
    MCH(8,  wp16, wp17, az16, az17, an16, an17)                                    \
    MCH(9,  wp18, wp19, az18, az19, an18, an19)                                    \
    MCH(10, wp20, wp21, az20, az21, an20, an21)                                    \
    MCH(11, wp22, wp23, az22, az23, an22, an23)                                    \
    MCH(12, wp24, wp25, az24, az25, an24, an25)                                    \
    MCH(13, wp26, wp27, az26, az27, an26, an27)                                    \
    MCH(14, wp28, wp29, az28, az29, an28, an29)                                    \
    MCH(15, wp30, wp31, az30, az31, an30, an31)                                    \
    ar = qred(ar); az = qred(az); an = qred(an); }

// phase-2: one uint4 of ys f16 (8 k) -> 24 MACs
#define PCH(YV, WA, WB, WC, WD, ZA, ZB, ZC, ZD, NA, NB, NC, ND)                    \
  { FMA2VH(ar, WA, (YV).x) FMA2VH(ar, WB, (YV).y)                                  \
    FMA2VH(ar, WC, (YV).z) FMA2VH(ar, WD, (YV).w)                                  \
    FMA2AH(az, ZA, (YV).x) FMA2AH(az, ZB, (YV).y)                                  \
    FMA2AH(az, ZC, (YV).z) FMA2AH(az, ZD, (YV).w)                                  \
    FMA2AH(an, NA, (YV).x) FMA2AH(an, NB, (YV).y)                                  \
    FMA2AH(an, NC, (YV).z) FMA2AH(an, ND, (YV).w) }

__global__ __attribute__((amdgpu_flat_work_group_size(NTHR, NTHR), amdgpu_waves_per_eu(4, 4)))
void gru_forecast(
    const float* __restrict__ x,
    const float* __restrict__ Wih0, const float* __restrict__ Whh0,
    const float* __restrict__ bih0, const float* __restrict__ bhh0,
    const float* __restrict__ Wih1, const float* __restrict__ Whh1,
    const float* __restrict__ bih1, const float* __restrict__ bhh1,
    const float* __restrict__ Wdih, const float* __restrict__ Wdhh,
    const float* __restrict__ bdih, const float* __restrict__ bdhh,
    const float* __restrict__ Wo, const float* __restrict__ bo,
    float* __restrict__ out, __half* __restrict__ ys, __half* __restrict__ gi) {
  __shared__ SmemT s;
  const int tid = threadIdx.x;
  const int b = blockIdx.x;
  const int j = tid >> 2;    // output/gate row (0..255)
  const int q = tid & 3;     // k-quad
  const int k0 = q << 6;
  unsigned int wp00,wp01,wp02,wp03,wp04,wp05,wp06,wp07,wp08,wp09,wp10,wp11,wp12,wp13,
      wp14,wp15,wp16,wp17,wp18,wp19,wp20,wp21,wp22,wp23,wp24,wp25,wp26,wp27,wp28,wp29,
      wp30,wp31;  // r-gate: 32 arch VGPRs
  unsigned int   // z/n gates: 64 AGPRs (acc half of the unified RF, R7-proven)
      az00,az01,az02,az03,az04,az05,az06,az07,az08,az09,az10,az11,az12,az13,az14,az15,
      az16,az17,az18,az19,az20,az21,az22,az23,az24,az25,az26,az27,az28,az29,az30,az31,
      an00,an01,an02,an03,an04,an05,an06,an07,an08,an09,an10,an11,an12,an13,an14,an15,
      an16,an17,an18,an19,an20,an21,an22,an23,an24,an25,an26,an27,an28,an29,an30,an31;
  float ar, az, an;

  // ---------------- Phase 1: encoder GRU layer 0 (input_size=1) ----------------
  if (tid < LSEQ) s.xv[tid] = x[(size_t)b * LSEQ + tid];
  if (tid < 768) { s.wih[tid] = Wih0[tid]; s.bih[tid] = bih0[tid]; s.bhh[tid] = bhh0[tid]; }
  if (tid < 272) ((float*)s.h[0])[tid] = 0.f;
  LOADW(Whh0);
  __syncthreads();

  int pb = 0;
  for (int t = 0; t < LSEQ; ++t) {
    MATVEC(s.h[pb][q]);
    const float xt = s.xv[t];
    const float ghr = ar + s.bhh[j], ghz = az + s.bhh[j + 256], ghn = an + s.bhh[j + 512];
    const float r = sigm(fmaf(xt, s.wih[j], s.bih[j]) + ghr);
    const float z = sigm(fmaf(xt, s.wih[j + 256], s.bih[j + 256]) + ghz);
    const float n = tanh_(fmaf(r, ghn, fmaf(xt, s.wih[j + 512], s.bih[j + 512])));
    const float hold = s.h[pb][j >> 6][j & 63];
    const float hn = fmaf(z, hold - n, n);
    if (q == 0) {
      s.h[pb ^ 1][j >> 6][j & 63] = hn;
      ys[((size_t)b * LSEQ + t) * HDIM + j] = __float2half(hn);  // |h| < 1: f16-safe
    }
    pb ^= 1;
    __syncthreads();
  }

  // ---- Phase 2: GI1 = ys0 @ W_ih1.T + b_ih1 — no recurrence, NO barriers ----
  // R8 BUG FIX: weight rows are register-distributed, so a wave can only produce
  // its OWN 16 j-rows. Every thread therefore loops over ALL t (its quad is a
  // self-contained K=256 row engine); the 16 waves together cover all 768 rows
  // per t. ys reads are L1-broadcast across the 16 j-groups sharing a q-slice.
  LOADW(Wih1);
  {
    const float bi_r = bih1[j], bi_z = bih1[j + 256], bi_n = bih1[j + 512];
#pragma unroll 1
    for (int t = 0; t < LSEQ; ++t) {
      const uint4* y4 = (const uint4*)(ys + ((size_t)b * LSEQ + t) * HDIM + k0);
      ar = 0.f; az = 0.f; an = 0.f;
      {
        uint4 a0 = y4[0], a1 = y4[1], a2 = y4[2], a3 = y4[3];
        PCH(a0, wp00,wp01,wp02,wp03, az00,az01,az02,az03, an00,an01,an02,an03)
        PCH(a1, wp04,wp05,wp06,wp07, az04,az05,az06,az07, an04,an05,an06,an07)
        PCH(a2, wp08,wp09,wp10,wp11, az08,az09,az10,az11, an08,an09,an10,an11)
        PCH(a3, wp12,wp13,wp14,wp15, az12,az13,az14,az15, an12,an13,an14,an15)
      }
      {
        uint4 a0 = y4[4], a1 = y4[5], a2 = y4[6], a3 = y4[7];
        PCH(a0, wp16,wp17,wp18,wp19, az16,az17,az18,az19, an16,an17,an18,an19)
        PCH(a1, wp20,wp21,wp22,wp23, az20,az21,az22,az23, an20,an21,an22,an23)
        PCH(a2, wp24,wp25,wp26,wp27, az24,az25,az26,az27, an24,an25,an26,an27)
        PCH(a3, wp28,wp29,wp30,wp31, az28,az29,az30,az31, an28,an29,an30,an31)
      }
      ar = qred(ar); az = qred(az); an = qred(an);
      const size_t o = ((size_t)b * LSEQ + t) * 768;
      if (q == 0) gi[o + j] = __float2half(ar + bi_r);
      else if (q == 1) gi[o + j + 256] = __float2half(az + bi_z);
      else if (q == 2) gi[o + j + 512] = __float2half(an + bi_n);
    }
  }
  __syncthreads();  // drains vmcnt: gi visible to all waves before phase 3

  // ---------------- Phase 3: encoder GRU layer 1 (uses precomputed GI) --------
  LOADW(Whh1);
  if (tid < 768) s.bhh[tid] = bhh1[tid];
  if (tid < 272) ((float*)s.h[0])[tid] = 0.f;
  __syncthreads();
  pb = 0;
  for (int t = 0; t < LSEQ; ++t) {
    const size_t o = ((size_t)b * LSEQ + t) * 768;
    const float gr = __half2float(gi[o + j]);           // prefetch; latency hidden
    const float gz = __half2float(gi[o + j + 256]);
    const float gn = __half2float(gi[o + j + 512]);
    MATVEC(s.h[pb][q]);
    const float ghr = ar + s.bhh[j], ghz = az + s.bhh[j + 256], ghn = an + s.bhh[j + 512];
    const float r = sigm(gr + ghr);
    const float z = sigm(gz + ghz);
    const float n = tanh_(fmaf(r, ghn, gn));
    const float hold = s.h[pb][j >> 6][j & 63];
    const float hn = fmaf(z, hold - n, n);
    if (q == 0) s.h[pb ^ 1][j >> 6][j & 63] = hn;
    pb ^= 1;
    __syncthreads();
  }

  // ---------------- Phase 4: autoregressive decoder (96 steps) ----------------
  LOADW(Wdhh);
  if (tid < 768) { s.wih[tid] = Wdih[tid]; s.bih[tid] = bdih[tid]; s.bhh[tid] = bdhh[tid]; }
  if (tid < HDIM) s.wo[tid] = Wo[tid];
  if (tid == 0) s.inp = 0.f;
  const float bov = bo[0];
  __syncthreads();
  for (int t = 0; t < PRED; ++t) {
    const float it = s.inp;
    MATVEC(s.h[pb][q]);
    const float ghr = ar + s.bhh[j], ghz = az + s.bhh[j + 256], ghn = an + s.bhh[j + 512];
    const float r = sigm(fmaf(it, s.wih[j], s.bih[j]) + ghr);
    const float z = sigm(fmaf(it, s.wih[j + 256], s.bih[j + 256]) + ghz);
    const float n = tanh_(fmaf(r, ghn, fmaf(it, s.wih[j + 512], s.bih[j + 512])));
    const float hold = s.h[pb][j >> 6][j & 63];
    const float hn = fmaf(z, hold - n, n);
    float c = (q == 0) ? s.wo[j] * hn : 0.f;
#pragma unroll
    for (int off = 1; off < 64; off <<= 1) c += __shfl_xor(c, off);
    if (q == 0) s.h[pb ^ 1][j >> 6][j & 63] = hn;
    if ((tid & 63) == 0) s.red[tid >> 6] = c;
    pb ^= 1;
    __syncthreads();
    if (tid == 0) {
      float ov = bov;
#pragma unroll
      for (int i2 = 0; i2 < 16; ++i2) ov += s.red[i2];
      out[(size_t)b * PRED + t] = ov;
      s.inp = ov;
    }
    __syncthreads();
  }
}

extern "C" void kernel_launch(void* const* d_in, const int* in_sizes, int n_in,
                              void* d_out, int out_size, void* d_ws, size_t ws_size,
                              hipStream_t stream) {
  const float* x    = (const float*)d_in[0];
  const float* Wih0 = (const float*)d_in[1];
  const float* Whh0 = (const float*)d_in[2];
  const float* bih0 = (const float*)d_in[3];
  const float* bhh0 = (const float*)d_in[4];
  const float* Wih1 = (const float*)d_in[5];
  const float* Whh1 = (const float*)d_in[6];
  const float* bih1 = (const float*)d_in[7];
  const float* bhh1 = (const float*)d_in[8];
  const float* Wdih = (const float*)d_in[9];
  const float* Wdhh = (const float*)d_in[10];
  const float* bdih = (const float*)d_in[11];
  const float* bdhh = (const float*)d_in[12];
  const float* Wo   = (const float*)d_in[13];
  const float* bo   = (const float*)d_in[14];

  // ws layout: ys0 (f16, 64 MiB) | GI1 (f16, 192 MiB)
  __half* ys = (__half*)d_ws;
  __half* gi = ys + (size_t)256 * 512 * 256;

  gru_forecast<<<256, NTHR, 0, stream>>>(x, Wih0, Whh0, bih0, bhh0,
                                         Wih1, Whh1, bih1, bhh1,
                                         Wdih, Wdhh, bdih, bdhh, Wo, bo,
                                         (float*)d_out, ys, gi);
}

// Round 11
// 5083.353 us; speedup vs baseline: 14.4279x; 1.0122x over previous
//
#include <hip/hip_runtime.h>
#include <hip/hip_fp16.h>

#define HDIM 256
#define LSEQ 512
#define PRED 96
#define NTHR 1024

__device__ __forceinline__ float sigm(float x) { return 1.f / (1.f + __expf(-x)); }
__device__ __forceinline__ float tanh_(float x) { float t = __expf(2.f * x); return 1.f - 2.f / (t + 1.f); }

// quad butterfly (lanes xor 1, xor 2) via DPP quad_perm — pure VALU, no LDS pipe.
__device__ __forceinline__ float qred(float v) {
  v += __builtin_bit_cast(float, __builtin_amdgcn_update_dpp(
           0, __builtin_bit_cast(int, v), 0xB1, 0xF, 0xF, true));  // quad_perm [1,0,3,2]
  v += __builtin_bit_cast(float, __builtin_amdgcn_update_dpp(
           0, __builtin_bit_cast(int, v), 0x4E, 0xF, 0xF, true));  // quad_perm [2,3,0,1]
  return v;
}

struct SmemT {
  float h[2][4][68];  // [buf][quad][64+pad4]; 68 dwords = 17 float4 (16B-aligned bases)
  float xv[LSEQ];
  float wih[768];     // rank-1 input weights for scalar-input phases
  float bih[768];
  float bhh[768];
  float wo[HDIM];
  float red[16];
  float inp;
};

// pack 2 fp32 -> 1 u32 of 2 f16 (RN) — arch-resident weight pair
#define WPK(D, X, Y)                                                               \
  { __half2 _h = __floats2half2_rn((X), (Y));                                      \
    (D) = __builtin_bit_cast(unsigned int, _h); }

// AGPR write (R7-proven): claims the acc half of the unified RF
#define AW(A, X, Y)                                                                \
  { __half2 _h = __floats2half2_rn((X), (Y));                                      \
    unsigned int _u = __builtin_bit_cast(unsigned int, _h);                        \
    asm("v_accvgpr_write_b32 %0, %1" : "=a"(A) : "v"(_u)); }
#define AWP(A, F2) AW(A, (F2).x, (F2).y)

// This thread's 3 gate rows (64-wide k-slice) of [768][256] fp32:
// r -> 32 arch u32 pairs; z,n -> 64 AGPR pairs.  (unchanged from R9)
#define LOADW(PTR)                                                                 \
  {                                                                                \
    const float4* r4 = (const float4*)((PTR) + (size_t)j * HDIM + k0);             \
    float4 f;                                                                      \
    f=r4[0];  WPK(wp00,f.x,f.y) WPK(wp01,f.z,f.w)                                  \
    f=r4[1];  WPK(wp02,f.x,f.y) WPK(wp03,f.z,f.w)                                  \
    f=r4[2];  WPK(wp04,f.x,f.y) WPK(wp05,f.z,f.w)                                  \
    f=r4[3];  WPK(wp06,f.x,f.y) WPK(wp07,f.z,f.w)                                  \
    f=r4[4];  WPK(wp08,f.x,f.y) WPK(wp09,f.z,f.w)                                  \
    f=r4[5];  WPK(wp10,f.x,f.y) WPK(wp11,f.z,f.w)                                  \
    f=r4[6];  WPK(wp12,f.x,f.y) WPK(wp13,f.z,f.w)                                  \
    f=r4[7];  WPK(wp14,f.x,f.y) WPK(wp15,f.z,f.w)                                  \
    f=r4[8];  WPK(wp16,f.x,f.y) WPK(wp17,f.z,f.w)                                  \
    f=r4[9];  WPK(wp18,f.x,f.y) WPK(wp19,f.z,f.w)                                  \
    f=r4[10]; WPK(wp20,f.x,f.y) WPK(wp21,f.z,f.w)                                  \
    f=r4[11]; WPK(wp22,f.x,f.y) WPK(wp23,f.z,f.w)                                  \
    f=r4[12]; WPK(wp24,f.x,f.y) WPK(wp25,f.z,f.w)                                  \
    f=r4[13]; WPK(wp26,f.x,f.y) WPK(wp27,f.z,f.w)                                  \
    f=r4[14]; WPK(wp28,f.x,f.y) WPK(wp29,f.z,f.w)                                  \
    f=r4[15]; WPK(wp30,f.x,f.y) WPK(wp31,f.z,f.w)                                  \
    const float2* z2 = (const float2*)((PTR) + (size_t)(j + 256) * HDIM + k0);     \
    const float2* n2 = (const float2*)((PTR) + (size_t)(j + 512) * HDIM + k0);     \
    AWP(az00,z2[0])  AWP(az01,z2[1])  AWP(az02,z2[2])  AWP(az03,z2[3])             \
    AWP(az04,z2[4])  AWP(az05,z2[5])  AWP(az06,z2[6])  AWP(az07,z2[7])             \
    AWP(az08,z2[8])  AWP(az09,z2[9])  AWP(az10,z2[10]) AWP(az11,z2[11])            \
    AWP(az12,z2[12]) AWP(az13,z2[13]) AWP(az14,z2[14]) AWP(az15,z2[15])            \
    AWP(az16,z2[16]) AWP(az17,z2[17]) AWP(az18,z2[18]) AWP(az19,z2[19])            \
    AWP(az20,z2[20]) AWP(az21,z2[21]) AWP(az22,z2[22]) AWP(az23,z2[23])            \
    AWP(az24,z2[24]) AWP(az25,z2[25]) AWP(az26,z2[26]) AWP(az27,z2[27])            \
    AWP(az28,z2[28]) AWP(az29,z2[29]) AWP(az30,z2[30]) AWP(az31,z2[31])            \
    AWP(an00,n2[0])  AWP(an01,n2[1])  AWP(an02,n2[2])  AWP(an03,n2[3])             \
    AWP(an04,n2[4])  AWP(an05,n2[5])  AWP(an06,n2[6])  AWP(an07,n2[7])             \
    AWP(an08,n2[8])  AWP(an09,n2[9])  AWP(an10,n2[10]) AWP(an11,n2[11])            \
    AWP(an12,n2[12]) AWP(an13,n2[13]) AWP(an14,n2[14]) AWP(an15,n2[15])            \
    AWP(an16,n2[16]) AWP(an17,n2[17]) AWP(an18,n2[18]) AWP(an19,n2[19])            \
    AWP(an20,n2[20]) AWP(an21,n2[21]) AWP(an22,n2[22]) AWP(an23,n2[23])            \
    AWP(an24,n2[24]) AWP(an25,n2[25]) AWP(an26,n2[26]) AWP(an27,n2[27])            \
    AWP(an28,n2[28]) AWP(an29,n2[29]) AWP(an30,n2[30]) AWP(an31,n2[31])            \
  }

// Pipelined 16-inst block: one float4 of f32 h -> 12 MACs + 4 AGPR reads.
// Gate rotation ar->az->an keeps same-acc ops >=3 slots apart; reads >=2 slots
// ahead of first use -> no RAW stalls on the in-order SIMD. Accumulation order
// per gate identical to R9 (bit-identical result).
#define MIXCH(HV, WA, WB, ZA, ZB, NA, NB)                                          \
  asm("v_accvgpr_read_b32 %[t0], %[za]\n\t"                                        \
      "v_accvgpr_read_b32 %[t1], %[na]\n\t"                                        \
      "v_fma_mix_f32 %[ar], %[wa], %[hx], %[ar] op_sel:[0,0,0] op_sel_hi:[1,0,0]\n\t" \
      "v_accvgpr_read_b32 %[t2], %[zb]\n\t"                                        \
      "v_fma_mix_f32 %[az], %[t0], %[hx], %[az] op_sel:[0,0,0] op_sel_hi:[1,0,0]\n\t" \
      "v_fma_mix_f32 %[an], %[t1], %[hx], %[an] op_sel:[0,0,0] op_sel_hi:[1,0,0]\n\t" \
      "v_fma_mix_f32 %[ar], %[wa], %[hy], %[ar] op_sel:[1,0,0] op_sel_hi:[1,0,0]\n\t" \
      "v_fma_mix_f32 %[az], %[t0], %[hy], %[az] op_sel:[1,0,0] op_sel_hi:[1,0,0]\n\t" \
      "v_accvgpr_read_b32 %[t3], %[nb]\n\t"                                        \
      "v_fma_mix_f32 %[an], %[t1], %[hy], %[an] op_sel:[1,0,0] op_sel_hi:[1,0,0]\n\t" \
      "v_fma_mix_f32 %[ar], %[wb], %[hz], %[ar] op_sel:[0,0,0] op_sel_hi:[1,0,0]\n\t" \
      "v_fma_mix_f32 %[az], %[t2], %[hz], %[az] op_sel:[0,0,0] op_sel_hi:[1,0,0]\n\t" \
      "v_fma_mix_f32 %[an], %[t3], %[hz], %[an] op_sel:[0,0,0] op_sel_hi:[1,0,0]\n\t" \
      "v_fma_mix_f32 %[ar], %[wb], %[hw], %[ar] op_sel:[1,0,0] op_sel_hi:[1,0,0]\n\t" \
      "v_fma_mix_f32 %[az], %[t2], %[hw], %[az] op_sel:[1,0,0] op_sel_hi:[1,0,0]\n\t" \
      "v_fma_mix_f32 %[an], %[t3], %[hw], %[an] op_sel:[1,0,0] op_sel_hi:[1,0,0]"  \
      : [ar]"+v"(ar), [az]"+v"(az), [an]"+v"(an),                                  \
        [t0]"=&v"(t0_), [t1]"=&v"(t1_), [t2]"=&v"(t2_), [t3]"=&v"(t3_)             \
      : [wa]"v"(WA), [wb]"v"(WB), [za]"a"(ZA), [zb]"a"(ZB), [na]"a"(NA), [nb]"a"(NB), \
        [hx]"v"((HV).x), [hy]"v"((HV).y), [hz]"v"((HV).z), [hw]"v"((HV).w));

#define MF(P, WA, WB, ZA, ZB, NA, NB)                                              \
  { const float4 _c = h4[P]; MIXCH(_c, WA, WB, ZA, ZB, NA, NB) }

// 3-gate dot over this thread's 64-wide f32 k-slice + quad butterfly.
#define MATVECF(HP)                                                                \
  { ar = 0.f; az = 0.f; an = 0.f; unsigned int t0_, t1_, t2_, t3_;                 \
    const float4* h4 = (const float4*)(HP);                                        \
    MF(0,  wp00, wp01, az00, az01, an00, an01)                                     \
    MF(1,  wp02, wp03, az02, az03, an02, an03)                                     \
    MF(2,  wp04, wp05, az04, az05, an04, an05)                                     \
    MF(3,  wp06, wp07, az06, az07, an06, an07)                                     \
    MF(4,  wp08, wp09, az08, az09, an08, an09)                                     \
    MF(5,  wp10, wp11, az10, az11, an10, an11)                                     \
    MF(6,  wp12, wp13, az12, az13, an12, an13)                                     \
    MF(7,  wp14, wp15, az14, az15, an14, an15)                                     \
    MF(8,  wp16, wp17, az16, az17, an16, an17)                                     \
    MF(9,  wp18, wp19, az18, az19, an18, an19)                                     \
    MF(10, wp20, wp21, az20, az21, an20, an21)                                     \
    MF(11, wp22, wp23, az22, az23, an22, an23)                                     \
    MF(12, wp24, wp25, az24, az25, an24, an25)                                     \
    MF(13, wp26, wp27, az26, az27, an26, an27)                                     \
    MF(14, wp28, wp29, az28, az29, an28, an29)                                     \
    MF(15, wp30, wp31, az30, az31, an30, an31)                                     \
    ar = qred(ar); az = qred(az); an = qred(an); }

// Pipelined 32-inst block: one uint4 of f16 ys (8 k) -> 24 MACs + 8 AGPR reads.
// Same rotation discipline; both operands f16 (op_sel_hi [1,1,0]).
#define MH(YV, WA, WB, WC, WD, ZA, ZB, ZC, ZD, NA, NB, NC, ND)                     \
  asm("v_accvgpr_read_b32 %[t0], %[za]\n\t"                                        \
      "v_accvgpr_read_b32 %[t1], %[na]\n\t"                                        \
      "v_fma_mix_f32 %[ar], %[wa], %[y0], %[ar] op_sel:[0,0,0] op_sel_hi:[1,1,0]\n\t" \
      "v_accvgpr_read_b32 %[t2], %[zb]\n\t"                                        \
      "v_fma_mix_f32 %[az], %[t0], %[y0], %[az] op_sel:[0,0,0] op_sel_hi:[1,1,0]\n\t" \
      "v_fma_mix_f32 %[an], %[t1], %[y0], %[an] op_sel:[0,0,0] op_sel_hi:[1,1,0]\n\t" \
      "v_fma_mix_f32 %[ar], %[wa], %[y0], %[ar] op_sel:[1,1,0] op_sel_hi:[1,1,0]\n\t" \
      "v_fma_mix_f32 %[az], %[t0], %[y0], %[az] op_sel:[1,1,0] op_sel_hi:[1,1,0]\n\t" \
      "v_accvgpr_read_b32 %[t3], %[nb]\n\t"                                        \
      "v_fma_mix_f32 %[an], %[t1], %[y0], %[an] op_sel:[1,1,0] op_sel_hi:[1,1,0]\n\t" \
      "v_fma_mix_f32 %[ar], %[wb], %[y1], %[ar] op_sel:[0,0,0] op_sel_hi:[1,1,0]\n\t" \
      "v_fma_mix_f32 %[az], %[t2], %[y1], %[az] op_sel:[0,0,0] op_sel_hi:[1,1,0]\n\t" \
      "v_accvgpr_read_b32 %[t0], %[zc]\n\t"                                        \
      "v_fma_mix_f32 %[an], %[t3], %[y1], %[an] op_sel:[0,0,0] op_sel_hi:[1,1,0]\n\t" \
      "v_fma_mix_f32 %[ar], %[wb], %[y1], %[ar] op_sel:[1,1,0] op_sel_hi:[1,1,0]\n\t" \
      "v_fma_mix_f32 %[az], %[t2], %[y1], %[az] op_sel:[1,1,0] op_sel_hi:[1,1,0]\n\t" \
      "v_accvgpr_read_b32 %[t1], %[nc]\n\t"                                        \
      "v_fma_mix_f32 %[an], %[t3], %[y1], %[an] op_sel:[1,1,0] op_sel_hi:[1,1,0]\n\t" \
      "v_fma_mix_f32 %[ar], %[wc], %[y2], %[ar] op_sel:[0,0,0] op_sel_hi:[1,1,0]\n\t" \
      "v_fma_mix_f32 %[az], %[t0], %[y2], %[az] op_sel:[0,0,0] op_sel_hi:[1,1,0]\n\t" \
      "v_accvgpr_read_b32 %[t2], %[zd]\n\t"                                        \
      "v_fma_mix_f32 %[an], %[t1], %[y2], %[an] op_sel:[0,0,0] op_sel_hi:[1,1,0]\n\t" \
      "v_fma_mix_f32 %[ar], %[wc], %[y2], %[ar] op_sel:[1,1,0] op_sel_hi:[1,1,0]\n\t" \
      "v_fma_mix_f32 %[az], %[t0], %[y2], %[az] op_sel:[1,1,0] op_sel_hi:[1,1,0]\n\t" \
      "v_accvgpr_read_b32 %[t3], %[nd]\n\t"                                        \
      "v_fma_mix_f32 %[an], %[t1], %[y2], %[an] op_sel:[1,1,0] op_sel_hi:[1,1,0]\n\t" \
      "v_fma_mix_f32 %[ar], %[wd], %[y3], %[ar] op_sel:[0,0,0] op_sel_hi:[1,1,0]\n\t" \
      "v_fma_mix_f32 %[az], %[t2], %[y3], %[az] op_sel:[0,0,0] op_sel_hi:[1,1,0]\n\t" \
      "v_fma_mix_f32 %[an], %[t3], %[y3], %[an] op_sel:[0,0,0] op_sel_hi:[1,1,0]\n\t" \
      "v_fma_mix_f32 %[ar], %[wd], %[y3], %[ar] op_sel:[1,1,0] op_sel_hi:[1,1,0]\n\t" \
      "v_fma_mix_f32 %[az], %[t2], %[y3], %[az] op_sel:[1,1,0] op_sel_hi:[1,1,0]\n\t" \
      "v_fma_mix_f32 %[an], %[t3], %[y3], %[an] op_sel:[1,1,0] op_sel_hi:[1,1,0]"  \
      : [ar]"+v"(ar), [az]"+v"(az), [an]"+v"(an),                                  \
        [t0]"=&v"(t0_), [t1]"=&v"(t1_), [t2]"=&v"(t2_), [t3]"=&v"(t3_)             \
      : [wa]"v"(WA), [wb]"v"(WB), [wc]"v"(WC), [wd]"v"(WD),                        \
        [za]"a"(ZA), [zb]"a"(ZB), [zc]"a"(ZC), [zd]"a"(ZD),                        \
        [na]"a"(NA), [nb]"a"(NB), [nc]"a"(NC), [nd]"a"(ND),                        \
        [y0]"v"((YV).x), [y1]"v"((YV).y), [y2]"v"((YV).z), [y3]"v"((YV).w));

#define MY(P, WA, WB, WC, WD, ZA, ZB, ZC, ZD, NA, NB, NC, ND)                      \
  { const uint4 _y = y4[P]; MH(_y, WA, WB, WC, WD, ZA, ZB, ZC, ZD, NA, NB, NC, ND) }

// 3-gate dot over this thread's 64-wide f16 k-slice (global ys) + butterfly.
#define MATVECH(SRC)                                                               \
  { ar = 0.f; az = 0.f; an = 0.f; unsigned int t0_, t1_, t2_, t3_;                 \
    const uint4* y4 = (const uint4*)(SRC);                                         \
    MY(0, wp00,wp01,wp02,wp03, az00,az01,az02,az03, an00,an01,an02,an03)           \
    MY(1, wp04,wp05,wp06,wp07, az04,az05,az06,az07, an04,an05,an06,an07)           \
    MY(2, wp08,wp09,wp10,wp11, az08,az09,az10,az11, an08,an09,an10,an11)           \
    MY(3, wp12,wp13,wp14,wp15, az12,az13,az14,az15, an12,an13,an14,an15)           \
    MY(4, wp16,wp17,wp18,wp19, az16,az17,az18,az19, an16,an17,an18,an19)           \
    MY(5, wp20,wp21,wp22,wp23, az20,az21,az22,az23, an20,an21,an22,an23)           \
    MY(6, wp24,wp25,wp26,wp27, az24,az25,az26,az27, an24,an25,an26,an27)           \
    MY(7, wp28,wp29,wp30,wp31, az28,az29,az30,az31, an28,an29,an30,an31)           \
    ar = qred(ar); az = qred(az); an = qred(an); }

__global__ __attribute__((amdgpu_flat_work_group_size(NTHR, NTHR), amdgpu_waves_per_eu(4, 4)))
void gru_forecast(
    const float* __restrict__ x,
    const float* __restrict__ Wih0, const float* __restrict__ Whh0,
    const float* __restrict__ bih0, const float* __restrict__ bhh0,
    const float* __restrict__ Wih1, const float* __restrict__ Whh1,
    const float* __restrict__ bih1, const float* __restrict__ bhh1,
    const float* __restrict__ Wdih, const float* __restrict__ Wdhh,
    const float* __restrict__ bdih, const float* __restrict__ bdhh,
    const float* __restrict__ Wo, const float* __restrict__ bo,
    float* __restrict__ out, __half* __restrict__ ys, __half* __restrict__ gi) {
  __shared__ SmemT s;
  const int tid = threadIdx.x;
  const int b = blockIdx.x;
  const int j = tid >> 2;    // output/gate row (0..255)
  const int q = tid & 3;     // k-quad
  const int k0 = q << 6;
  unsigned int wp00,wp01,wp02,wp03,wp04,wp05,wp06,wp07,wp08,wp09,wp10,wp11,wp12,wp13,
      wp14,wp15,wp16,wp17,wp18,wp19,wp20,wp21,wp22,wp23,wp24,wp25,wp26,wp27,wp28,wp29,
      wp30,wp31;  // r-gate: 32 arch VGPRs
  unsigned int   // z/n gates: 64 AGPRs (acc half of the unified RF, R7-proven)
      az00,az01,az02,az03,az04,az05,az06,az07,az08,az09,az10,az11,az12,az13,az14,az15,
      az16,az17,az18,az19,az20,az21,az22,az23,az24,az25,az26,az27,az28,az29,az30,az31,
      an00,an01,an02,an03,an04,an05,an06,an07,an08,an09,an10,an11,an12,an13,an14,an15,
      an16,an17,an18,an19,an20,an21,an22,an23,an24,an25,an26,an27,an28,an29,an30,an31;
  float ar, az, an;

  // ---------------- Phase 1: encoder GRU layer 0 (input_size=1) ----------------
  if (tid < LSEQ) s.xv[tid] = x[(size_t)b * LSEQ + tid];
  if (tid < 768) { s.wih[tid] = Wih0[tid]; s.bih[tid] = bih0[tid]; s.bhh[tid] = bhh0[tid]; }
  if (tid < 272) ((float*)s.h[0])[tid] = 0.f;
  LOADW(Whh0);
  __syncthreads();

  int pb = 0;
  for (int t = 0; t < LSEQ; ++t) {
    MATVECF(&s.h[pb][q][0]);
    const float xt = s.xv[t];
    const float ghr = ar + s.bhh[j], ghz = az + s.bhh[j + 256], ghn = an + s.bhh[j + 512];
    const float r = sigm(fmaf(xt, s.wih[j], s.bih[j]) + ghr);
    const float z = sigm(fmaf(xt, s.wih[j + 256], s.bih[j + 256]) + ghz);
    const float n = tanh_(fmaf(r, ghn, fmaf(xt, s.wih[j + 512], s.bih[j + 512])));
    const float hold = s.h[pb][j >> 6][j & 63];
    const float hn = fmaf(z, hold - n, n);
    if (q == 0) {
      s.h[pb ^ 1][j >> 6][j & 63] = hn;
      ys[((size_t)b * LSEQ + t) * HDIM + j] = __float2half(hn);  // |h| < 1: f16-safe
    }
    pb ^= 1;
    __syncthreads();
  }

  // ---- Phase 2: GI1 = ys0 @ W_ih1.T + b_ih1 — no recurrence, NO barriers ----
  // Weight rows are register-distributed: every thread loops over ALL t (its
  // quad is a self-contained K=256 row engine); 16 waves cover 768 rows per t.
  LOADW(Wih1);
  {
    const float bi_r = bih1[j], bi_z = bih1[j + 256], bi_n = bih1[j + 512];
#pragma unroll 1
    for (int t = 0; t < LSEQ; ++t) {
      MATVECH(ys + ((size_t)b * LSEQ + t) * HDIM + k0);
      const size_t o = ((size_t)b * LSEQ + t) * 768;
      if (q == 0) gi[o + j] = __float2half(ar + bi_r);
      else if (q == 1) gi[o + j + 256] = __float2half(az + bi_z);
      else if (q == 2) gi[o + j + 512] = __float2half(an + bi_n);
    }
  }
  __syncthreads();  // drains vmcnt: gi visible to all waves before phase 3

  // ---------------- Phase 3: encoder GRU layer 1 (uses precomputed GI) --------
  LOADW(Whh1);
  if (tid < 768) s.bhh[tid] = bhh1[tid];
  if (tid < 272) ((float*)s.h[0])[tid] = 0.f;
  __syncthreads();
  pb = 0;
  for (int t = 0; t < LSEQ; ++t) {
    const size_t o = ((size_t)b * LSEQ + t) * 768;
    const float gr = __half2float(gi[o + j]);           // prefetch; latency hidden
    const float gz = __half2float(gi[o + j + 256]);
    const float gn = __half2float(gi[o + j + 512]);
    MATVECF(&s.h[pb][q][0]);
    const float ghr = ar + s.bhh[j], ghz = az + s.bhh[j + 256], ghn = an + s.bhh[j + 512];
    const float r = sigm(gr + ghr);
    const float z = sigm(gz + ghz);
    const float n = tanh_(fmaf(r, ghn, gn));
    const float hold = s.h[pb][j >> 6][j & 63];
    const float hn = fmaf(z, hold - n, n);
    if (q == 0) s.h[pb ^ 1][j >> 6][j & 63] = hn;
    pb ^= 1;
    __syncthreads();
  }

  // ---------------- Phase 4: autoregressive decoder (96 steps) ----------------
  LOADW(Wdhh);
  if (tid < 768) { s.wih[tid] = Wdih[tid]; s.bih[tid] = bdih[tid]; s.bhh[tid] = bdhh[tid]; }
  if (tid < HDIM) s.wo[tid] = Wo[tid];
  if (tid == 0) s.inp = 0.f;
  const float bov = bo[0];
  __syncthreads();
  for (int t = 0; t < PRED; ++t) {
    const float it = s.inp;
    MATVECF(&s.h[pb][q][0]);
    const float ghr = ar + s.bhh[j], ghz = az + s.bhh[j + 256], ghn = an + s.bhh[j + 512];
    const float r = sigm(fmaf(it, s.wih[j], s.bih[j]) + ghr);
    const float z = sigm(fmaf(it, s.wih[j + 256], s.bih[j + 256]) + ghz);
    const float n = tanh_(fmaf(r, ghn, fmaf(it, s.wih[j + 512], s.bih[j + 512])));
    const float hold = s.h[pb][j >> 6][j & 63];
    const float hn = fmaf(z, hold - n, n);
    float c = (q == 0) ? s.wo[j] * hn : 0.f;
#pragma unroll
    for (int off = 1; off < 64; off <<= 1) c += __shfl_xor(c, off);
    if (q == 0) s.h[pb ^ 1][j >> 6][j & 63] = hn;
    if ((tid & 63) == 0) s.red[tid >> 6] = c;
    pb ^= 1;
    __syncthreads();
    if (tid == 0) {
      float ov = bov;
#pragma unroll
      for (int i2 = 0; i2 < 16; ++i2) ov += s.red[i2];
      out[(size_t)b * PRED + t] = ov;
      s.inp = ov;
    }
    __syncthreads();
  }
}

extern "C" void kernel_launch(void* const* d_in, const int* in_sizes, int n_in,
                              void* d_out, int out_size, void* d_ws, size_t ws_size,
                              hipStream_t stream) {
  const float* x    = (const float*)d_in[0];
  const float* Wih0 = (const float*)d_in[1];
  const float* Whh0 = (const float*)d_in[2];
  const float* bih0 = (const float*)d_in[3];
  const float* bhh0 = (const float*)d_in[4];
  const float* Wih1 = (const float*)d_in[5];
  const float* Whh1 = (const float*)d_in[6];
  const float* bih1 = (const float*)d_in[7];
  const float* bhh1 = (const float*)d_in[8];
  const float* Wdih = (const float*)d_in[9];
  const float* Wdhh = (const float*)d_in[10];
  const float* bdih = (const float*)d_in[11];
  const float* bdhh = (const float*)d_in[12];
  const float* Wo   = (const float*)d_in[13];
  const float* bo   = (const float*)d_in[14];

  // ws layout: ys0 (f16, 64 MiB) | GI1 (f16, 192 MiB)
  __half* ys = (__half*)d_ws;
  __half* gi = ys + (size_t)256 * 512 * 256;

  gru_forecast<<<256, NTHR, 0, stream>>>(x, Wih0, Whh0, bih0, bhh0,
                                         Wih1, Whh1, bih1, bhh1,
                                         Wdih, Wdhh, bdih, bdhh, Wo, bo,
                                         (float*)d_out, ys, gi);
}

// Round 13
// 3993.248 us; speedup vs baseline: 18.3665x; 1.2730x over previous
//
#include <hip/hip_runtime.h>
#include <hip/hip_fp16.h>

#define HDIM 256
#define LSEQ 512
#define PRED 96
#define NTHR 1024

__device__ __forceinline__ float sigm(float x) { return 1.f / (1.f + __expf(-x)); }
__device__ __forceinline__ float tanh_(float x) { float t = __expf(2.f * x); return 1.f - 2.f / (t + 1.f); }

// quad butterfly (lanes xor 1, xor 2) via DPP quad_perm — pure VALU, no LDS pipe.
__device__ __forceinline__ float qred(float v) {
  v += __builtin_bit_cast(float, __builtin_amdgcn_update_dpp(
           0, __builtin_bit_cast(int, v), 0xB1, 0xF, 0xF, true));  // quad_perm [1,0,3,2]
  v += __builtin_bit_cast(float, __builtin_amdgcn_update_dpp(
           0, __builtin_bit_cast(int, v), 0x4E, 0xF, 0xF, true));  // quad_perm [2,3,0,1]
  return v;
}

struct SmemT {
  float h[2][4][68];  // [buf][quad][64+pad4]
  float xv[LSEQ];
  float wih[768];     // rank-1 input weights for scalar-input phases
  float bih[768];
  float bhh[768];
  float wo[HDIM];
  float red[16];
  float inp;
};

// pack 2 fp32 -> 1 u32 of 2 f16 (RN) — arch-resident weight pair
#define WPK(D, X, Y)                                                               \
  { __half2 _h = __floats2half2_rn((X), (Y));                                      \
    (D) = __builtin_bit_cast(unsigned int, _h); }

// AGPR write (R7-proven): claims the acc half of the unified RF
#define AW(A, X, Y)                                                                \
  { __half2 _h = __floats2half2_rn((X), (Y));                                      \
    unsigned int _u = __builtin_bit_cast(unsigned int, _h);                        \
    asm("v_accvgpr_write_b32 %0, %1" : "=a"(A) : "v"(_u)); }
#define AWP(A, F2) AW(A, (F2).x, (F2).y)

// This thread's 3 gate rows (64-wide k-slice) of [768][256] fp32:
// r -> 32 arch u32 pairs; z,n -> 64 AGPR pairs.
#define LOADW(PTR)                                                                 \
  {                                                                                \
    const float4* r4 = (const float4*)((PTR) + (size_t)j * HDIM + k0);             \
    float4 f;                                                                      \
    f=r4[0];  WPK(wp00,f.x,f.y) WPK(wp01,f.z,f.w)                                  \
    f=r4[1];  WPK(wp02,f.x,f.y) WPK(wp03,f.z,f.w)                                  \
    f=r4[2];  WPK(wp04,f.x,f.y) WPK(wp05,f.z,f.w)                                  \
    f=r4[3];  WPK(wp06,f.x,f.y) WPK(wp07,f.z,f.w)                                  \
    f=r4[4];  WPK(wp08,f.x,f.y) WPK(wp09,f.z,f.w)                                  \
    f=r4[5];  WPK(wp10,f.x,f.y) WPK(wp11,f.z,f.w)                                  \
    f=r4[6];  WPK(wp12,f.x,f.y) WPK(wp13,f.z,f.w)                                  \
    f=r4[7];  WPK(wp14,f.x,f.y) WPK(wp15,f.z,f.w)                                  \
    f=r4[8];  WPK(wp16,f.x,f.y) WPK(wp17,f.z,f.w)                                  \
    f=r4[9];  WPK(wp18,f.x,f.y) WPK(wp19,f.z,f.w)                                  \
    f=r4[10]; WPK(wp20,f.x,f.y) WPK(wp21,f.z,f.w)                                  \
    f=r4[11]; WPK(wp22,f.x,f.y) WPK(wp23,f.z,f.w)                                  \
    f=r4[12]; WPK(wp24,f.x,f.y) WPK(wp25,f.z,f.w)                                  \
    f=r4[13]; WPK(wp26,f.x,f.y) WPK(wp27,f.z,f.w)                                  \
    f=r4[14]; WPK(wp28,f.x,f.y) WPK(wp29,f.z,f.w)                                  \
    f=r4[15]; WPK(wp30,f.x,f.y) WPK(wp31,f.z,f.w)                                  \
    const float2* z2 = (const float2*)((PTR) + (size_t)(j + 256) * HDIM + k0);     \
    const float2* n2 = (const float2*)((PTR) + (size_t)(j + 512) * HDIM + k0);     \
    AWP(az00,z2[0])  AWP(az01,z2[1])  AWP(az02,z2[2])  AWP(az03,z2[3])             \
    AWP(az04,z2[4])  AWP(az05,z2[5])  AWP(az06,z2[6])  AWP(az07,z2[7])             \
    AWP(az08,z2[8])  AWP(az09,z2[9])  AWP(az10,z2[10]) AWP(az11,z2[11])            \
    AWP(az12,z2[12]) AWP(az13,z2[13]) AWP(az14,z2[14]) AWP(az15,z2[15])            \
    AWP(az16,z2[16]) AWP(az17,z2[17]) AWP(az18,z2[18]) AWP(az19,z2[19])            \
    AWP(az20,z2[20]) AWP(az21,z2[21]) AWP(az22,z2[22]) AWP(az23,z2[23])            \
    AWP(az24,z2[24]) AWP(az25,z2[25]) AWP(az26,z2[26]) AWP(az27,z2[27])            \
    AWP(az28,z2[28]) AWP(az29,z2[29]) AWP(az30,z2[30]) AWP(az31,z2[31])            \
    AWP(an00,n2[0])  AWP(an01,n2[1])  AWP(an02,n2[2])  AWP(an03,n2[3])             \
    AWP(an04,n2[4])  AWP(an05,n2[5])  AWP(an06,n2[6])  AWP(an07,n2[7])             \
    AWP(an08,n2[8])  AWP(an09,n2[9])  AWP(an10,n2[10]) AWP(an11,n2[11])            \
    AWP(an12,n2[12]) AWP(an13,n2[13]) AWP(an14,n2[14]) AWP(an15,n2[15])            \
    AWP(an16,n2[16]) AWP(an17,n2[17]) AWP(an18,n2[18]) AWP(an19,n2[19])            \
    AWP(an20,n2[20]) AWP(an21,n2[21]) AWP(an22,n2[22]) AWP(an23,n2[23])            \
    AWP(an24,n2[24]) AWP(an25,n2[25]) AWP(an26,n2[26]) AWP(an27,n2[27])            \
    AWP(an28,n2[28]) AWP(an29,n2[29]) AWP(an30,n2[30]) AWP(an31,n2[31])            \
  }

// Pipelined 16-inst block (R11-proven): one float4 of f32 h -> 12 MACs + 4 reads.
#define MIXCH(HV, WA, WB, ZA, ZB, NA, NB)                                          \
  asm("v_accvgpr_read_b32 %[t0], %[za]\n\t"                                        \
      "v_accvgpr_read_b32 %[t1], %[na]\n\t"                                        \
      "v_fma_mix_f32 %[ar], %[wa], %[hx], %[ar] op_sel:[0,0,0] op_sel_hi:[1,0,0]\n\t" \
      "v_accvgpr_read_b32 %[t2], %[zb]\n\t"                                        \
      "v_fma_mix_f32 %[az], %[t0], %[hx], %[az] op_sel:[0,0,0] op_sel_hi:[1,0,0]\n\t" \
      "v_fma_mix_f32 %[an], %[t1], %[hx], %[an] op_sel:[0,0,0] op_sel_hi:[1,0,0]\n\t" \
      "v_fma_mix_f32 %[ar], %[wa], %[hy], %[ar] op_sel:[1,0,0] op_sel_hi:[1,0,0]\n\t" \
      "v_fma_mix_f32 %[az], %[t0], %[hy], %[az] op_sel:[1,0,0] op_sel_hi:[1,0,0]\n\t" \
      "v_accvgpr_read_b32 %[t3], %[nb]\n\t"                                        \
      "v_fma_mix_f32 %[an], %[t1], %[hy], %[an] op_sel:[1,0,0] op_sel_hi:[1,0,0]\n\t" \
      "v_fma_mix_f32 %[ar], %[wb], %[hz], %[ar] op_sel:[0,0,0] op_sel_hi:[1,0,0]\n\t" \
      "v_fma_mix_f32 %[az], %[t2], %[hz], %[az] op_sel:[0,0,0] op_sel_hi:[1,0,0]\n\t" \
      "v_fma_mix_f32 %[an], %[t3], %[hz], %[an] op_sel:[0,0,0] op_sel_hi:[1,0,0]\n\t" \
      "v_fma_mix_f32 %[ar], %[wb], %[hw], %[ar] op_sel:[1,0,0] op_sel_hi:[1,0,0]\n\t" \
      "v_fma_mix_f32 %[az], %[t2], %[hw], %[az] op_sel:[1,0,0] op_sel_hi:[1,0,0]\n\t" \
      "v_fma_mix_f32 %[an], %[t3], %[hw], %[an] op_sel:[1,0,0] op_sel_hi:[1,0,0]"  \
      : [ar]"+v"(ar), [az]"+v"(az), [an]"+v"(an),                                  \
        [t0]"=&v"(t0_), [t1]"=&v"(t1_), [t2]"=&v"(t2_), [t3]"=&v"(t3_)             \
      : [wa]"v"(WA), [wb]"v"(WB), [za]"a"(ZA), [zb]"a"(ZB), [na]"a"(NA), [nb]"a"(NB), \
        [hx]"v"((HV).x), [hy]"v"((HV).y), [hz]"v"((HV).z), [hw]"v"((HV).w));

#define MF(P, WA, WB, ZA, ZB, NA, NB)                                              \
  { const float4 _c = h4[P]; MIXCH(_c, WA, WB, ZA, ZB, NA, NB) }

#define MATVECF(HP)                                                                \
  { ar = 0.f; az = 0.f; an = 0.f; unsigned int t0_, t1_, t2_, t3_;                 \
    const float4* h4 = (const float4*)(HP);                                        \
    MF(0,  wp00, wp01, az00, az01, an00, an01)                                     \
    MF(1,  wp02, wp03, az02, az03, an02, an03)                                     \
    MF(2,  wp04, wp05, az04, az05, an04, an05)                                     \
    MF(3,  wp06, wp07, az06, az07, an06, an07)                                     \
    MF(4,  wp08, wp09, az08, az09, an08, an09)                                     \
    MF(5,  wp10, wp11, az10, az11, an10, an11)                                     \
    MF(6,  wp12, wp13, az12, az13, an12, an13)                                     \
    MF(7,  wp14, wp15, az14, az15, an14, an15)                                     \
    MF(8,  wp16, wp17, az16, az17, an16, an17)                                     \
    MF(9,  wp18, wp19, az18, az19, an18, an19)                                     \
    MF(10, wp20, wp21, az20, az21, an20, an21)                                     \
    MF(11, wp22, wp23, az22, az23, an22, an23)                                     \
    MF(12, wp24, wp25, az24, az25, an24, an25)                                     \
    MF(13, wp26, wp27, az26, az27, an26, an27)                                     \
    MF(14, wp28, wp29, az28, az29, an28, an29)                                     \
    MF(15, wp30, wp31, az30, az31, an30, an31)                                     \
    ar = qred(ar); az = qred(az); an = qred(an); }

#define DECL_WREGS                                                                 \
  unsigned int wp00,wp01,wp02,wp03,wp04,wp05,wp06,wp07,wp08,wp09,wp10,wp11,wp12,   \
      wp13,wp14,wp15,wp16,wp17,wp18,wp19,wp20,wp21,wp22,wp23,wp24,wp25,wp26,wp27,  \
      wp28,wp29,wp30,wp31;                                                         \
  unsigned int                                                                     \
      az00,az01,az02,az03,az04,az05,az06,az07,az08,az09,az10,az11,az12,az13,az14,az15, \
      az16,az17,az18,az19,az20,az21,az22,az23,az24,az25,az26,az27,az28,az29,az30,az31, \
      an00,an01,an02,an03,an04,an05,an06,an07,an08,an09,an10,an11,an12,an13,an14,an15, \
      an16,an17,an18,an19,an20,an21,an22,an23,an24,an25,an26,an27,an28,an29,an30,an31; \
  float ar, az, an;

// =================== Kernel 1: encoder GRU layer 0 (sequential) ===============
__global__ __attribute__((amdgpu_flat_work_group_size(NTHR, NTHR), amdgpu_waves_per_eu(4, 4)))
void gru_p1(const float* __restrict__ x,
            const float* __restrict__ Wih0, const float* __restrict__ Whh0,
            const float* __restrict__ bih0, const float* __restrict__ bhh0,
            __half* __restrict__ ys) {
  __shared__ SmemT s;
  const int tid = threadIdx.x;
  const int b = blockIdx.x;
  const int j = tid >> 2;
  const int q = tid & 3;
  const int k0 = q << 6;
  DECL_WREGS

  if (tid < LSEQ) s.xv[tid] = x[(size_t)b * LSEQ + tid];
  if (tid < 768) { s.wih[tid] = Wih0[tid]; s.bih[tid] = bih0[tid]; s.bhh[tid] = bhh0[tid]; }
  if (tid < 272) ((float*)s.h[0])[tid] = 0.f;
  LOADW(Whh0);
  __syncthreads();

  int pb = 0;
  for (int t = 0; t < LSEQ; ++t) {
    MATVECF(&s.h[pb][q][0]);
    const float xt = s.xv[t];
    const float ghr = ar + s.bhh[j], ghz = az + s.bhh[j + 256], ghn = an + s.bhh[j + 512];
    const float r = sigm(fmaf(xt, s.wih[j], s.bih[j]) + ghr);
    const float z = sigm(fmaf(xt, s.wih[j + 256], s.bih[j + 256]) + ghz);
    const float n = tanh_(fmaf(r, ghn, fmaf(xt, s.wih[j + 512], s.bih[j + 512])));
    const float hold = s.h[pb][j >> 6][j & 63];
    const float hn = fmaf(z, hold - n, n);
    if (q == 0) {
      s.h[pb ^ 1][j >> 6][j & 63] = hn;
      ys[((size_t)b * LSEQ + t) * HDIM + j] = __float2half(hn);  // |h| < 1: f16-safe
    }
    pb ^= 1;
    __syncthreads();
  }
}

// ============ Kernel 2: GI1 = ys0 @ W_ih1^T + b_ih1 as an MFMA GEMM ===========
// M=768 (gate rows), N=131072 (b,t pairs), K=256. One block = one 16-col n-tile;
// 4 waves x 12 M-tiles; B-frags (ys, f16) register-resident; A converted fp32->f16
// on load (same RN as the VALU path). Layouts (m89/m91-verified, dtype-indep):
//   A[m=lane&15][k=quad*8+i]  B[k=quad*8+i][n=lane&15]  D[m=quad*4+reg][n=lane&15]
typedef _Float16 f16x8 __attribute__((ext_vector_type(8)));
typedef float f32x4 __attribute__((ext_vector_type(4)));

__global__ __launch_bounds__(256) void gemm_gi(
    const float* __restrict__ Wih1, const float* __restrict__ bih1,
    const __half* __restrict__ ys, __half* __restrict__ gi) {
  const int lane = threadIdx.x & 63;
  const int wv = threadIdx.x >> 6;            // 0..3
  const size_t bt0 = (size_t)blockIdx.x << 4; // 16 (b,t) columns
  const int n = lane & 15, q = lane >> 4;

  // preload all 8 B fragments (full K for this n-tile): 32 VGPRs
  f16x8 bfr[8];
  const __half* yrow = ys + (bt0 + n) * HDIM + q * 8;
#pragma unroll
  for (int kk = 0; kk < 8; ++kk) bfr[kk] = *(const f16x8*)(yrow + kk * 32);

#pragma unroll 1
  for (int mt = 0; mt < 12; ++mt) {
    const int j0 = (wv * 12 + mt) << 4;
    const float* arow = Wih1 + (size_t)(j0 + n) * HDIM + q * 8;
    f32x4 acc = {0.f, 0.f, 0.f, 0.f};
#pragma unroll
    for (int kk = 0; kk < 8; ++kk) {
      const float4 a0 = *(const float4*)(arow + kk * 32);
      const float4 a1 = *(const float4*)(arow + kk * 32 + 4);
      f16x8 af;
      af[0] = (_Float16)a0.x; af[1] = (_Float16)a0.y;
      af[2] = (_Float16)a0.z; af[3] = (_Float16)a0.w;
      af[4] = (_Float16)a1.x; af[5] = (_Float16)a1.y;
      af[6] = (_Float16)a1.z; af[7] = (_Float16)a1.w;
      acc = __builtin_amdgcn_mfma_f32_16x16x32_f16(af, bfr[kk], acc, 0, 0, 0);
    }
    const int jr = j0 + (q << 2);             // D rows m = q*4 + reg
    __half o4[4];
#pragma unroll
    for (int r2 = 0; r2 < 4; ++r2) o4[r2] = __float2half(acc[r2] + bih1[jr + r2]);
    *(uint2*)(gi + (bt0 + n) * 768 + jr) = *(uint2*)o4;
  }
}

// ====== Kernel 3: encoder GRU layer 1 (uses gi) + autoregressive decoder ======
__global__ __attribute__((amdgpu_flat_work_group_size(NTHR, NTHR), amdgpu_waves_per_eu(4, 4)))
void gru_p34(const float* __restrict__ Whh1, const float* __restrict__ bhh1,
             const float* __restrict__ Wdih, const float* __restrict__ Wdhh,
             const float* __restrict__ bdih, const float* __restrict__ bdhh,
             const float* __restrict__ Wo, const float* __restrict__ bo,
             const __half* __restrict__ gi, float* __restrict__ out) {
  __shared__ SmemT s;
  const int tid = threadIdx.x;
  const int b = blockIdx.x;
  const int j = tid >> 2;
  const int q = tid & 3;
  const int k0 = q << 6;
  DECL_WREGS

  // ---------------- Phase 3: encoder GRU layer 1 ----------------
  LOADW(Whh1);
  if (tid < 768) s.bhh[tid] = bhh1[tid];
  if (tid < 272) ((float*)s.h[0])[tid] = 0.f;
  __syncthreads();
  int pb = 0;
  for (int t = 0; t < LSEQ; ++t) {
    const size_t o = ((size_t)b * LSEQ + t) * 768;
    const float gr = __half2float(gi[o + j]);           // prefetch; latency hidden
    const float gz = __half2float(gi[o + j + 256]);
    const float gn = __half2float(gi[o + j + 512]);
    MATVECF(&s.h[pb][q][0]);
    const float ghr = ar + s.bhh[j], ghz = az + s.bhh[j + 256], ghn = an + s.bhh[j + 512];
    const float r = sigm(gr + ghr);
    const float z = sigm(gz + ghz);
    const float n = tanh_(fmaf(r, ghn, gn));
    const float hold = s.h[pb][j >> 6][j & 63];
    const float hn = fmaf(z, hold - n, n);
    if (q == 0) s.h[pb ^ 1][j >> 6][j & 63] = hn;
    pb ^= 1;
    __syncthreads();
  }

  // ---------------- Phase 4: autoregressive decoder (96 steps) ----------------
  LOADW(Wdhh);
  if (tid < 768) { s.wih[tid] = Wdih[tid]; s.bih[tid] = bdih[tid]; s.bhh[tid] = bdhh[tid]; }
  if (tid < HDIM) s.wo[tid] = Wo[tid];
  if (tid == 0) s.inp = 0.f;
  const float bov = bo[0];
  __syncthreads();
  for (int t = 0; t < PRED; ++t) {
    const float it = s.inp;
    MATVECF(&s.h[pb][q][0]);
    const float ghr = ar + s.bhh[j], ghz = az + s.bhh[j + 256], ghn = an + s.bhh[j + 512];
    const float r = sigm(fmaf(it, s.wih[j], s.bih[j]) + ghr);
    const float z = sigm(fmaf(it, s.wih[j + 256], s.bih[j + 256]) + ghz);
    const float n = tanh_(fmaf(r, ghn, fmaf(it, s.wih[j + 512], s.bih[j + 512])));
    const float hold = s.h[pb][j >> 6][j & 63];
    const float hn = fmaf(z, hold - n, n);
    float c = (q == 0) ? s.wo[j] * hn : 0.f;
#pragma unroll
    for (int off = 1; off < 64; off <<= 1) c += __shfl_xor(c, off);
    if (q == 0) s.h[pb ^ 1][j >> 6][j & 63] = hn;
    if ((tid & 63) == 0) s.red[tid >> 6] = c;
    pb ^= 1;
    __syncthreads();
    if (tid == 0) {
      float ov = bov;
#pragma unroll
      for (int i2 = 0; i2 < 16; ++i2) ov += s.red[i2];
      out[(size_t)b * PRED + t] = ov;
      s.inp = ov;
    }
    __syncthreads();
  }
}

extern "C" void kernel_launch(void* const* d_in, const int* in_sizes, int n_in,
                              void* d_out, int out_size, void* d_ws, size_t ws_size,
                              hipStream_t stream) {
  const float* x    = (const float*)d_in[0];
  const float* Wih0 = (const float*)d_in[1];
  const float* Whh0 = (const float*)d_in[2];
  const float* bih0 = (const float*)d_in[3];
  const float* bhh0 = (const float*)d_in[4];
  const float* Wih1 = (const float*)d_in[5];
  const float* Whh1 = (const float*)d_in[6];
  const float* bih1 = (const float*)d_in[7];
  const float* bhh1 = (const float*)d_in[8];
  const float* Wdih = (const float*)d_in[9];
  const float* Wdhh = (const float*)d_in[10];
  const float* bdih = (const float*)d_in[11];
  const float* bdhh = (const float*)d_in[12];
  const float* Wo   = (const float*)d_in[13];
  const float* bo   = (const float*)d_in[14];

  // ws layout: ys0 (f16, 64 MiB) | GI1 (f16, 192 MiB)
  __half* ys = (__half*)d_ws;
  __half* gi = ys + (size_t)256 * 512 * 256;

  gru_p1<<<256, NTHR, 0, stream>>>(x, Wih0, Whh0, bih0, bhh0, ys);
  gemm_gi<<<(256 * 512) / 16, 256, 0, stream>>>(Wih1, bih1, ys, gi);
  gru_p34<<<256, NTHR, 0, stream>>>(Whh1, bhh1, Wdih, Wdhh, bdih, bdhh, Wo, bo,
                                    gi, (float*)d_out);
}